// Round 2
// baseline (2492.196 us; speedup 1.0000x reference)
//
#include <hip/hip_runtime.h>
#include <hip/hip_cooperative_groups.h>

namespace coop = cooperative_groups;

#define BB 16
#define NN 2048
#define MM 2048
#define EPSF 1e-9f
#define SKIPT (-135.0f)   // exp2(arg) == 0 below this
#define LOG2E 1.4426950408889634f

typedef float v2f __attribute__((ext_vector_type(2)));

constexpr int CH = 64;       // stream chunk length (2 outputs/thread)
constexpr int PBLK = 1024;   // persistent grid: 4 blocks/CU on 256 CUs

// =================== shared device bodies (R0 atomic scheme) ===================

__device__ __forceinline__ void rowInit_body(
    int vbid, const float4* __restrict__ P1, const float4* __restrict__ P2,
    float* __restrict__ stRSacc, float coef, float4* sCol)
{
    const int chunks = MM / CH;                   // 32
    const int bpb = (NN / 512) * chunks;          // 128
    const int batch = vbid / bpb;
    const int rem   = vbid % bpb;
    const int rg    = rem / chunks;
    const int ic    = rem % chunks;
    const int t     = threadIdx.x;

    if (t < CH) sCol[t] = P2[batch * MM + ic * CH + t];
    __syncthreads();

    const int row0 = batch * NN + rg * 512 + t;
    const int row1 = row0 + 256;
    const float4 p0 = P1[row0];
    const float4 p1 = P1[row1];
    const v2f px = {p0.x, p1.x}, py = {p0.y, p1.y}, pz = {p0.z, p1.z};
    v2f rs = {0.0f, 0.0f};
#pragma unroll 4
    for (int ii = 0; ii < CH; ++ii) {
        const float4 q = sCol[ii];
        const v2f dx = px - q.x, dy = py - q.y, dz = pz - q.z;
        const v2f g = coef * (dx*dx + dy*dy + dz*dz);
        if (__ballot((g.x > SKIPT) || (g.y > SKIPT))) {
            v2f e;
            e.x = __builtin_amdgcn_exp2f(g.x);
            e.y = __builtin_amdgcn_exp2f(g.y);
            rs += e;
        }
    }
    atomicAdd(&stRSacc[row0], rs.x);
    atomicAdd(&stRSacc[row1], rs.y);
}

// MODE 0: j==0 (remL=1). MODE 1: general. MODE 2: j==9 (coef==0 -> e=scale).
template<int MODE, bool SPARSE>
__device__ __forceinline__ void colK_body(
    int vbid,
    const float4* __restrict__ P1, const float4* __restrict__ P2,
    const float* __restrict__ stRSr, const float* __restrict__ stUr,
    float* __restrict__ stRSz, float* __restrict__ stUz,
    const float* __restrict__ remLr, float* __restrict__ remLw,
    const float* __restrict__ scaler, float* __restrict__ scalew,
    float* __restrict__ stS, float* __restrict__ stT,
    float coef, float4* sRow)
{
    const int chunks = NN / CH;                   // 32
    const int bpb = (MM / 512) * chunks;          // 128
    const int batch = vbid / bpb;
    const int rem   = vbid % bpb;
    const int cgp   = rem / chunks;
    const int ic    = rem % chunks;
    const int t     = threadIdx.x;

    // prelude: finalize rows of this chunk (duplicated by 4 cg-blocks; identical values)
    if (t < CH) {
        const int gi = batch * NN + ic * CH + t;
        float L;
        if (MODE == 0) L = 1.0f;
        else           L = fmaxf(remLr[gi] - scaler[gi] * stUr[gi], 0.0f);
        remLw[gi] = L;
        const float sc = L / (stRSr[gi] + EPSF);
        scalew[gi] = sc;
        const float4 p = P1[gi];
        sRow[t] = make_float4(p.x, p.y, p.z, sc);
        stRSz[gi] = 0.0f; stUz[gi] = 0.0f;        // zero next accumulation parity
    }
    __syncthreads();

    const int col0 = batch * MM + cgp * 512 + t;
    const int col1 = col0 + 256;
    const float4 q0 = P2[col0];
    const float4 q1 = P2[col1];
    const v2f qx = {q0.x, q1.x}, qy = {q0.y, q1.y}, qz = {q0.z, q1.z};
    v2f s = {0.0f, 0.0f}, tt = {0.0f, 0.0f};
#pragma unroll 4
    for (int ii = 0; ii < CH; ++ii) {
        const float4 a = sRow[ii];
        const v2f dx = a.x - qx, dy = a.y - qy, dz = a.z - qz;
        const v2f d2 = dx*dx + dy*dy + dz*dz;
        if (SPARSE) {
            const v2f g = coef * d2;
            if (__ballot((g.x > SKIPT) || (g.y > SKIPT))) {
                v2f e;
                e.x = __builtin_amdgcn_exp2f(g.x);
                e.y = __builtin_amdgcn_exp2f(g.y);
                e *= a.w;
                v2f sq;
                sq.x = __builtin_amdgcn_sqrtf(d2.x);
                sq.y = __builtin_amdgcn_sqrtf(d2.y);
                s += e;
                tt += e * sq;
            }
        } else {
            v2f e;
            if (MODE == 2) { e.x = a.w; e.y = a.w; }
            else {
                const v2f g = coef * d2;
                e.x = a.w * __builtin_amdgcn_exp2f(g.x);
                e.y = a.w * __builtin_amdgcn_exp2f(g.y);
            }
            v2f sq;
            sq.x = __builtin_amdgcn_sqrtf(d2.x);
            sq.y = __builtin_amdgcn_sqrtf(d2.y);
            s += e;
            tt += e * sq;
        }
    }
    atomicAdd(&stS[col0], s.x);
    atomicAdd(&stT[col0], tt.x);
    atomicAdd(&stS[col1], s.y);
    atomicAdd(&stT[col1], tt.y);
}

// MODE 1: general. MODE 2: j==8 (rs = sum remR_9, u at coefP direct).
template<int MODE, bool SPARSE>
__device__ __forceinline__ void rowK_body(
    int vbid,
    const float4* __restrict__ P1, const float4* __restrict__ P2,
    const float* __restrict__ stSr, const float* __restrict__ stTr,
    float* __restrict__ stSz, float* __restrict__ stTz,
    const float* __restrict__ remRr, float* __restrict__ remRw,
    float* __restrict__ stRS, float* __restrict__ stU,
    float* __restrict__ out, float coefP, float coefN,
    float4* sCol, float* sPc)
{
    const int chunks = MM / CH;                   // 32
    const int bpb = (NN / 512) * chunks;          // 128
    const int batch = vbid / bpb;
    const int rem   = vbid % bpb;
    const int rg    = rem / chunks;
    const int ic    = rem % chunks;
    const int t     = threadIdx.x;

    // prelude: finalize cols of this chunk (duplicated by 4 rg-blocks; identical values)
    float c = 0.0f;
    if (t < CH) {
        const int gl = batch * MM + ic * CH + t;
        const float R  = remRr[gl];
        const float s  = stSr[gl];
        const float t2 = stTr[gl];
        const float sumr = s * R;
        const float cons = fminf(R / (sumr + EPSF), 1.0f);
        const float pcol = R * cons;
        const float Rn   = fmaxf(R - sumr * cons, 0.0f);
        remRw[gl] = Rn;
        const float4 p = P2[gl];
        sCol[t] = make_float4(p.x, p.y, p.z, Rn);
        sPc[t]  = pcol;
        stSz[gl] = 0.0f; stTz[gl] = 0.0f;         // zero next accumulation parity
        if (rg == 0) c = pcol * t2;               // cost contribution (once per chunk)
    }
    if (rg == 0) {
#pragma unroll
        for (int off = 32; off > 0; off >>= 1) c += __shfl_xor(c, off, 64);
        if (t == 0) atomicAdd(out + batch, c);
    }
    __syncthreads();

    const int row0 = batch * NN + rg * 512 + t;
    const int row1 = row0 + 256;
    const float4 p0 = P1[row0];
    const float4 p1 = P1[row1];
    const v2f px = {p0.x, p1.x}, py = {p0.y, p1.y}, pz = {p0.z, p1.z};
    v2f rs = {0.0f, 0.0f}, u = {0.0f, 0.0f};
#pragma unroll 4
    for (int ii = 0; ii < CH; ++ii) {
        const float4 q = sCol[ii];
        const float pc = sPc[ii];
        const v2f dx = px - q.x, dy = py - q.y, dz = pz - q.z;
        const v2f d2 = dx*dx + dy*dy + dz*dz;
        if (MODE == 1) {
            const v2f g = coefN * d2;
            if (SPARSE) {
                if (__ballot((g.x > SKIPT) || (g.y > SKIPT))) {
                    v2f en;
                    en.x = __builtin_amdgcn_exp2f(g.x);
                    en.y = __builtin_amdgcn_exp2f(g.y);
                    const v2f e2 = en * en;
                    const v2f e4 = e2 * e2;
                    u  += e4 * pc;                // e_prev = e_next^4
                    rs += en * q.w;
                }
            } else {
                v2f en;
                en.x = __builtin_amdgcn_exp2f(g.x);
                en.y = __builtin_amdgcn_exp2f(g.y);
                const v2f e2 = en * en;
                const v2f e4 = e2 * e2;
                u  += e4 * pc;
                rs += en * q.w;
            }
        } else {
            const v2f g = coefP * d2;
            v2f ep;
            ep.x = __builtin_amdgcn_exp2f(g.x);
            ep.y = __builtin_amdgcn_exp2f(g.y);
            u  += ep * pc;
            rs += q.w;                            // e_next = exp(0) = 1
        }
    }
    atomicAdd(&stRS[row0], rs.x);
    atomicAdd(&stU[row0], u.x);
    atomicAdd(&stRS[row1], rs.y);
    atomicAdd(&stU[row1], u.y);
}

__device__ __forceinline__ void finCost_body(
    int vbid,
    const float* __restrict__ stSr, const float* __restrict__ stTr,
    const float* __restrict__ remRr, float* __restrict__ out)
{
    const int idx = vbid * 256 + threadIdx.x;
    const int batch = idx / MM;
    const float R = remRr[idx];
    const float sumr = stSr[idx] * R;
    const float cons = fminf(R / (sumr + EPSF), 1.0f);
    float c = R * cons * stTr[idx];
#pragma unroll
    for (int off = 32; off > 0; off >>= 1) c += __shfl_xor(c, off, 64);
    if ((threadIdx.x & 63) == 0) atomicAdd(out + batch, c);
}

// =================== persistent cooperative kernel ===================

__global__ __launch_bounds__(256, 4) void emd_all(
    const float* __restrict__ xyz1, const float* __restrict__ xyz2,
    float4* __restrict__ P1, float4* __restrict__ P2,
    float* __restrict__ remL, float* __restrict__ scale, float* __restrict__ remR,
    float* __restrict__ stRS, float* __restrict__ stU,
    float* __restrict__ stS, float* __restrict__ stT,
    float* __restrict__ out)
{
    coop::grid_group gg = coop::this_grid();
    __shared__ float4 sQ[CH];
    __shared__ float  sPc[CH];
    const int bid = blockIdx.x;
    const int t   = threadIdx.x;
    const int BN = BB * NN, BM = BB * MM;

    // ---- phase: init ----
#pragma unroll 1
    for (int s = 0; s < 2; ++s) {
        const int i = (bid + s * PBLK) * 256 + t;
        if (i < BN) {
            P1[i] = make_float4(xyz1[3*i+0], xyz1[3*i+1], xyz1[3*i+2], 0.0f);
            stRS[i] = 0.0f; stRS[BN + i] = 0.0f;
            stU[i]  = 0.0f; stU[BN + i]  = 0.0f;
        }
        if (i < BM) {
            P2[i] = make_float4(xyz2[3*i+0], xyz2[3*i+1], xyz2[3*i+2], 0.0f);
            remR[i] = 1.0f;
            stS[i] = 0.0f; stS[BM + i] = 0.0f;
            stT[i] = 0.0f; stT[BM + i] = 0.0f;
        }
        if (i < BB) out[i] = 0.0f;
    }
    gg.sync();

    // ---- phase: rowInit (accumulates stRS parity 1 at coef[0]) ----
    {
        const float c0 = -16384.0f * LOG2E;
#pragma unroll 1
        for (int s = 0; s < 2; ++s) {
            rowInit_body(bid + s * PBLK, P1, P2, stRS + 1 * BN, c0, sQ);
            __syncthreads();
        }
    }
    gg.sync();

    // ---- levels ----
#pragma unroll 1
    for (int j = 0; j < 10; ++j) {
        const int p = j & 1, q = 1 - p;
        const float lvl = (j == 9) ? 0.0f : -__builtin_amdgcn_exp2f((float)(14 - 2*j));
        const float cj  = lvl * LOG2E;

#pragma unroll 1
        for (int s = 0; s < 2; ++s) {
            const int vb = bid + s * PBLK;
            if (j == 0)
                colK_body<0, true>(vb, P1, P2,
                    stRS + q*BN, stU + q*BN, stRS + p*BN, stU + p*BN,
                    remL + p*BN, remL + q*BN, scale + p*BN, scale + q*BN,
                    stS + p*BM, stT + p*BM, cj, sQ);
            else if (j <= 3)
                colK_body<1, true>(vb, P1, P2,
                    stRS + q*BN, stU + q*BN, stRS + p*BN, stU + p*BN,
                    remL + p*BN, remL + q*BN, scale + p*BN, scale + q*BN,
                    stS + p*BM, stT + p*BM, cj, sQ);
            else if (j == 9)
                colK_body<2, false>(vb, P1, P2,
                    stRS + q*BN, stU + q*BN, stRS + p*BN, stU + p*BN,
                    remL + p*BN, remL + q*BN, scale + p*BN, scale + q*BN,
                    stS + p*BM, stT + p*BM, cj, sQ);
            else
                colK_body<1, false>(vb, P1, P2,
                    stRS + q*BN, stU + q*BN, stRS + p*BN, stU + p*BN,
                    remL + p*BN, remL + q*BN, scale + p*BN, scale + q*BN,
                    stS + p*BM, stT + p*BM, cj, sQ);
            __syncthreads();
        }
        gg.sync();

        if (j < 9) {
            const float lvlN = (j == 8) ? 0.0f : -__builtin_amdgcn_exp2f((float)(12 - 2*j));
            const float cn   = lvlN * LOG2E;
#pragma unroll 1
            for (int s = 0; s < 2; ++s) {
                const int vb = bid + s * PBLK;
                if (j <= 2)
                    rowK_body<1, true>(vb, P1, P2,
                        stS + p*BM, stT + p*BM, stS + q*BM, stT + q*BM,
                        remR + p*BM, remR + q*BM,
                        stRS + p*BN, stU + p*BN, out, cj, cn, sQ, sPc);
                else if (j < 8)
                    rowK_body<1, false>(vb, P1, P2,
                        stS + p*BM, stT + p*BM, stS + q*BM, stT + q*BM,
                        remR + p*BM, remR + q*BM,
                        stRS + p*BN, stU + p*BN, out, cj, cn, sQ, sPc);
                else
                    rowK_body<2, false>(vb, P1, P2,
                        stS + p*BM, stT + p*BM, stS + q*BM, stT + q*BM,
                        remR + p*BM, remR + q*BM,
                        stRS + p*BN, stU + p*BN, out, cj, 0.0f, sQ, sPc);
                __syncthreads();
            }
            gg.sync();
        }
    }

    // ---- phase: finCost (level 9; parities: stS/stT 1, remR 1) ----
    if (bid < BM / 256)
        finCost_body(bid, stS + 1*BM, stT + 1*BM, remR + 1*BM, out);
}

// =================== fallback standalone kernels (R0 path) ===================

__global__ __launch_bounds__(256) void k_init(
    const float* __restrict__ xyz1, const float* __restrict__ xyz2,
    float4* __restrict__ P1, float4* __restrict__ P2,
    float* __restrict__ remR0,
    float* __restrict__ stRS, float* __restrict__ stU,
    float* __restrict__ stS, float* __restrict__ stT,
    float* __restrict__ out)
{
    const int i = blockIdx.x * 256 + threadIdx.x;
    const int BN = BB * NN, BM = BB * MM;
    if (i < BN) {
        P1[i] = make_float4(xyz1[3*i+0], xyz1[3*i+1], xyz1[3*i+2], 0.0f);
        stRS[i] = 0.0f; stRS[BN + i] = 0.0f;
        stU[i]  = 0.0f; stU[BN + i]  = 0.0f;
    }
    if (i < BM) {
        P2[i] = make_float4(xyz2[3*i+0], xyz2[3*i+1], xyz2[3*i+2], 0.0f);
        remR0[i] = 1.0f;
        stS[i] = 0.0f; stS[BM + i] = 0.0f;
        stT[i] = 0.0f; stT[BM + i] = 0.0f;
    }
    if (i < BB) out[i] = 0.0f;
}

__global__ __launch_bounds__(256) void k_rowInit(
    const float4* __restrict__ P1, const float4* __restrict__ P2,
    float* __restrict__ stRSacc, float coef)
{
    __shared__ float4 sCol[CH];
    rowInit_body(blockIdx.x, P1, P2, stRSacc, coef, sCol);
}

template<int MODE, bool SPARSE>
__global__ __launch_bounds__(256) void k_colK(
    const float4* __restrict__ P1, const float4* __restrict__ P2,
    const float* __restrict__ stRSr, const float* __restrict__ stUr,
    float* __restrict__ stRSz, float* __restrict__ stUz,
    const float* __restrict__ remLr, float* __restrict__ remLw,
    const float* __restrict__ scaler, float* __restrict__ scalew,
    float* __restrict__ stS, float* __restrict__ stT, float coef)
{
    __shared__ float4 sRow[CH];
    colK_body<MODE, SPARSE>(blockIdx.x, P1, P2, stRSr, stUr, stRSz, stUz,
                            remLr, remLw, scaler, scalew, stS, stT, coef, sRow);
}

template<int MODE, bool SPARSE>
__global__ __launch_bounds__(256) void k_rowK(
    const float4* __restrict__ P1, const float4* __restrict__ P2,
    const float* __restrict__ stSr, const float* __restrict__ stTr,
    float* __restrict__ stSz, float* __restrict__ stTz,
    const float* __restrict__ remRr, float* __restrict__ remRw,
    float* __restrict__ stRS, float* __restrict__ stU,
    float* __restrict__ out, float coefP, float coefN)
{
    __shared__ float4 sCol[CH];
    __shared__ float  sPc[CH];
    rowK_body<MODE, SPARSE>(blockIdx.x, P1, P2, stSr, stTr, stSz, stTz,
                            remRr, remRw, stRS, stU, out, coefP, coefN, sCol, sPc);
}

__global__ __launch_bounds__(256) void k_finCost(
    const float* __restrict__ stSr, const float* __restrict__ stTr,
    const float* __restrict__ remRr, float* __restrict__ out)
{
    finCost_body(blockIdx.x, stSr, stTr, remRr, out);
}

// =================== launch ===================

extern "C" void kernel_launch(void* const* d_in, const int* in_sizes, int n_in,
                              void* d_out, int out_size, void* d_ws, size_t ws_size,
                              hipStream_t stream)
{
    const float* xyz1 = (const float*)d_in[0];
    const float* xyz2 = (const float*)d_in[1];
    float* out = (float*)d_out;

    const int BN = BB * NN, BM = BB * MM;
    float4* P1 = (float4*)d_ws;
    float4* P2 = P1 + BN;
    float* remL  = (float*)(P2 + BM);       // [2][BN]
    float* scale = remL + 2 * BN;           // [2][BN]
    float* remR  = scale + 2 * BN;          // [2][BM]
    float* stRS  = remR + 2 * BM;           // [2][BN]
    float* stU   = stRS + 2 * BN;           // [2][BN]
    float* stS   = stU + 2 * BN;            // [2][BM]
    float* stT   = stS + 2 * BM;            // [2][BM]

    // decide once whether the persistent cooperative kernel can be resident
    static int coopOK = -1;
    if (coopOK < 0) {
        int maxb = 0;
        hipError_t oe = hipOccupancyMaxActiveBlocksPerMultiprocessor(&maxb, emd_all, 256, 0);
        coopOK = (oe == hipSuccess && maxb >= 4) ? 1 : 0;   // need 4 blocks/CU x 256 CU = 1024
    }

    if (coopOK == 1) {
        void* ka[12] = {
            (void*)&xyz1, (void*)&xyz2, (void*)&P1, (void*)&P2,
            (void*)&remL, (void*)&scale, (void*)&remR,
            (void*)&stRS, (void*)&stU, (void*)&stS, (void*)&stT,
            (void*)&out };
        hipError_t le = hipLaunchCooperativeKernel((const void*)emd_all,
                            dim3(PBLK), dim3(256), ka, 0, stream);
        if (le == hipSuccess) return;
        coopOK = 0;   // fall through to multi-kernel path this and future calls
    }

    // ---------------- fallback: R0 multi-kernel schedule ----------------
    k_init<<<dim3(BN / 256), dim3(256), 0, stream>>>(
        xyz1, xyz2, P1, P2, remR, stRS, stU, stS, stT, out);

    float coef[10];
    const double lv[10] = {-16384.0, -4096.0, -1024.0, -256.0, -64.0,
                           -16.0, -4.0, -1.0, -0.25, 0.0};
    for (int i = 0; i < 10; ++i) coef[i] = (float)(lv[i] * 1.4426950408889634);

    dim3 grid(BB * 4 * (NN / CH));          // 2048
    dim3 fgrid(BM / 256);                   // 128
    dim3 blk(256);

    k_rowInit<<<grid, blk, 0, stream>>>(P1, P2, stRS + 1 * BN, coef[0]);

    for (int j = 0; j < 10; ++j) {
        const int p = j & 1, q = 1 - p;
        if (j == 0)
            k_colK<0, true><<<grid, blk, 0, stream>>>(P1, P2,
                stRS + q*BN, stU + q*BN, stRS + p*BN, stU + p*BN,
                remL + p*BN, remL + q*BN, scale + p*BN, scale + q*BN,
                stS + p*BM, stT + p*BM, coef[0]);
        else if (j <= 3)
            k_colK<1, true><<<grid, blk, 0, stream>>>(P1, P2,
                stRS + q*BN, stU + q*BN, stRS + p*BN, stU + p*BN,
                remL + p*BN, remL + q*BN, scale + p*BN, scale + q*BN,
                stS + p*BM, stT + p*BM, coef[j]);
        else if (j == 9)
            k_colK<2, false><<<grid, blk, 0, stream>>>(P1, P2,
                stRS + q*BN, stU + q*BN, stRS + p*BN, stU + p*BN,
                remL + p*BN, remL + q*BN, scale + p*BN, scale + q*BN,
                stS + p*BM, stT + p*BM, coef[9]);
        else
            k_colK<1, false><<<grid, blk, 0, stream>>>(P1, P2,
                stRS + q*BN, stU + q*BN, stRS + p*BN, stU + p*BN,
                remL + p*BN, remL + q*BN, scale + p*BN, scale + q*BN,
                stS + p*BM, stT + p*BM, coef[j]);

        if (j < 9) {
            if (j <= 2)
                k_rowK<1, true><<<grid, blk, 0, stream>>>(P1, P2,
                    stS + p*BM, stT + p*BM, stS + q*BM, stT + q*BM,
                    remR + p*BM, remR + q*BM,
                    stRS + p*BN, stU + p*BN, out, coef[j], coef[j+1]);
            else if (j < 8)
                k_rowK<1, false><<<grid, blk, 0, stream>>>(P1, P2,
                    stS + p*BM, stT + p*BM, stS + q*BM, stT + q*BM,
                    remR + p*BM, remR + q*BM,
                    stRS + p*BN, stU + p*BN, out, coef[j], coef[j+1]);
            else
                k_rowK<2, false><<<grid, blk, 0, stream>>>(P1, P2,
                    stS + p*BM, stT + p*BM, stS + q*BM, stT + q*BM,
                    remR + p*BM, remR + q*BM,
                    stRS + p*BN, stU + p*BN, out, coef[8], 0.0f);
        }
    }
    k_finCost<<<fgrid, blk, 0, stream>>>(stS + 1*BM, stT + 1*BM, remR + 1*BM, out);
}

// Round 3
// 521.912 us; speedup vs baseline: 4.7751x; 4.7751x over previous
//
#include <hip/hip_runtime.h>

#define BB 16
#define NN 2048
#define MM 2048
#define EPSF 1e-9f
#define SKIPT (-135.0f)   // exp2(arg) == 0 below this

typedef float v4f __attribute__((ext_vector_type(4)));

constexpr int CH = 64;     // stream chunk length (4 outputs/thread)
// grid: BB batches x 2 groups(1024 own-points) x 32 chunks = 1024 blocks
// Schedule/parity identical to the 509us R0 scheme; only the streaming
// bodies changed from 2 to 4 outputs per thread (halves LDS instrs,
// ballot/branch and loop overhead per pair).

// ---------------- init ----------------
__global__ __launch_bounds__(256) void init_kernel(
    const float* __restrict__ xyz1, const float* __restrict__ xyz2,
    float4* __restrict__ P1, float4* __restrict__ P2,
    float* __restrict__ remR0,
    float* __restrict__ stRS, float* __restrict__ stU,
    float* __restrict__ stS, float* __restrict__ stT,
    float* __restrict__ out)
{
    const int t = blockIdx.x * 256 + threadIdx.x;   // 0 .. BB*NN-1
    if (t < BB * NN) {
        P1[t] = make_float4(xyz1[3*t+0], xyz1[3*t+1], xyz1[3*t+2], 0.0f);
        stRS[t] = 0.0f; stRS[BB*NN + t] = 0.0f;
        stU[t]  = 0.0f; stU[BB*NN + t]  = 0.0f;
    }
    if (t < BB * MM) {
        P2[t] = make_float4(xyz2[3*t+0], xyz2[3*t+1], xyz2[3*t+2], 0.0f);
        remR0[t] = 1.0f;
        stS[t] = 0.0f; stS[BB*MM + t] = 0.0f;
        stT[t] = 0.0f; stT[BB*MM + t] = 0.0f;
    }
    if (t < BB) out[t] = 0.0f;
}

// ---------------- rowInit: stRS[1] += sum_l exp(coef0*d2) (remR=1) ----------------
__global__ __launch_bounds__(256) void rowInit(
    const float4* __restrict__ P1, const float4* __restrict__ P2,
    float* __restrict__ stRSacc, float coef)
{
    __shared__ float4 sCol[CH];
    const int chunks = MM / CH;                   // 32
    const int bpb = (NN / 1024) * chunks;         // 64
    const int batch = blockIdx.x / bpb;
    const int rem   = blockIdx.x % bpb;
    const int rg    = rem / chunks;               // 0..1
    const int ic    = rem % chunks;
    const int t     = threadIdx.x;

    if (t < CH) sCol[t] = P2[batch * MM + ic * CH + t];
    __syncthreads();

    const int row0 = batch * NN + rg * 1024 + t;
    const float4 p0 = P1[row0];
    const float4 p1 = P1[row0 + 256];
    const float4 p2 = P1[row0 + 512];
    const float4 p3 = P1[row0 + 768];
    const v4f px = {p0.x, p1.x, p2.x, p3.x};
    const v4f py = {p0.y, p1.y, p2.y, p3.y};
    const v4f pz = {p0.z, p1.z, p2.z, p3.z};
    v4f rs = {0.0f, 0.0f, 0.0f, 0.0f};
#pragma unroll 4
    for (int ii = 0; ii < CH; ++ii) {
        const float4 q = sCol[ii];
        const v4f dx = px - q.x, dy = py - q.y, dz = pz - q.z;
        const v4f g = coef * (dx*dx + dy*dy + dz*dz);
        const float gm = fmaxf(fmaxf(g.x, g.y), fmaxf(g.z, g.w));
        if (__ballot(gm > SKIPT)) {
            v4f e;
            e.x = __builtin_amdgcn_exp2f(g.x);
            e.y = __builtin_amdgcn_exp2f(g.y);
            e.z = __builtin_amdgcn_exp2f(g.z);
            e.w = __builtin_amdgcn_exp2f(g.w);
            rs += e;
        }
    }
    atomicAdd(&stRSacc[row0],       rs.x);
    atomicAdd(&stRSacc[row0 + 256], rs.y);
    atomicAdd(&stRSacc[row0 + 512], rs.z);
    atomicAdd(&stRSacc[row0 + 768], rs.w);
}

// ---------------- colK: row-finalize prelude + column-partial stream ----------------
// MODE 0: j==0 (remL=1). MODE 1: general. MODE 2: j==9 (coef==0 -> e=scale).
template<int MODE, bool SPARSE>
__global__ __launch_bounds__(256) void colK(
    const float4* __restrict__ P1, const float4* __restrict__ P2,
    const float* __restrict__ stRSr, const float* __restrict__ stUr,
    float* __restrict__ stRSz, float* __restrict__ stUz,
    const float* __restrict__ remLr, float* __restrict__ remLw,
    const float* __restrict__ scaler, float* __restrict__ scalew,
    float* __restrict__ stS, float* __restrict__ stT,
    float coef)
{
    __shared__ float4 sRow[CH];                   // x1,y1,z1,scale_j
    const int chunks = NN / CH;                   // 32
    const int bpb = (MM / 1024) * chunks;         // 64
    const int batch = blockIdx.x / bpb;
    const int rem   = blockIdx.x % bpb;
    const int cg    = rem / chunks;               // 0..1
    const int ic    = rem % chunks;
    const int t     = threadIdx.x;

    // prelude: finalize rows of this chunk (duplicated by 2 cg-blocks; identical values)
    if (t < CH) {
        const int gi = batch * NN + ic * CH + t;
        float L;
        if (MODE == 0) L = 1.0f;
        else           L = fmaxf(remLr[gi] - scaler[gi] * stUr[gi], 0.0f);
        remLw[gi] = L;
        const float sc = L / (stRSr[gi] + EPSF);
        scalew[gi] = sc;
        const float4 p = P1[gi];
        sRow[t] = make_float4(p.x, p.y, p.z, sc);
        stRSz[gi] = 0.0f; stUz[gi] = 0.0f;        // zero next accumulation parity
    }
    __syncthreads();

    const int col0 = batch * MM + cg * 1024 + t;
    const float4 q0 = P2[col0];
    const float4 q1 = P2[col0 + 256];
    const float4 q2 = P2[col0 + 512];
    const float4 q3 = P2[col0 + 768];
    const v4f qx = {q0.x, q1.x, q2.x, q3.x};
    const v4f qy = {q0.y, q1.y, q2.y, q3.y};
    const v4f qz = {q0.z, q1.z, q2.z, q3.z};
    v4f s = {0.0f, 0.0f, 0.0f, 0.0f}, tt = {0.0f, 0.0f, 0.0f, 0.0f};
#pragma unroll 4
    for (int ii = 0; ii < CH; ++ii) {
        const float4 a = sRow[ii];
        const v4f dx = a.x - qx, dy = a.y - qy, dz = a.z - qz;
        const v4f d2 = dx*dx + dy*dy + dz*dz;
        if (SPARSE) {
            const v4f g = coef * d2;
            const float gm = fmaxf(fmaxf(g.x, g.y), fmaxf(g.z, g.w));
            if (__ballot(gm > SKIPT)) {
                v4f e;
                e.x = __builtin_amdgcn_exp2f(g.x);
                e.y = __builtin_amdgcn_exp2f(g.y);
                e.z = __builtin_amdgcn_exp2f(g.z);
                e.w = __builtin_amdgcn_exp2f(g.w);
                e *= a.w;
                v4f sq;
                sq.x = __builtin_amdgcn_sqrtf(d2.x);
                sq.y = __builtin_amdgcn_sqrtf(d2.y);
                sq.z = __builtin_amdgcn_sqrtf(d2.z);
                sq.w = __builtin_amdgcn_sqrtf(d2.w);
                s += e;
                tt += e * sq;
            }
        } else {
            v4f e;
            if (MODE == 2) { e.x = a.w; e.y = a.w; e.z = a.w; e.w = a.w; }
            else {
                const v4f g = coef * d2;
                e.x = a.w * __builtin_amdgcn_exp2f(g.x);
                e.y = a.w * __builtin_amdgcn_exp2f(g.y);
                e.z = a.w * __builtin_amdgcn_exp2f(g.z);
                e.w = a.w * __builtin_amdgcn_exp2f(g.w);
            }
            v4f sq;
            sq.x = __builtin_amdgcn_sqrtf(d2.x);
            sq.y = __builtin_amdgcn_sqrtf(d2.y);
            sq.z = __builtin_amdgcn_sqrtf(d2.z);
            sq.w = __builtin_amdgcn_sqrtf(d2.w);
            s += e;
            tt += e * sq;
        }
    }
    atomicAdd(&stS[col0],       s.x);
    atomicAdd(&stT[col0],       tt.x);
    atomicAdd(&stS[col0 + 256], s.y);
    atomicAdd(&stT[col0 + 256], tt.y);
    atomicAdd(&stS[col0 + 512], s.z);
    atomicAdd(&stT[col0 + 512], tt.z);
    atomicAdd(&stS[col0 + 768], s.w);
    atomicAdd(&stT[col0 + 768], tt.w);
}

// ---------------- rowK: col-finalize prelude + row-partial stream ----------------
// MODE 1: general. MODE 2: j==8 (rs = sum remR_9, u at coefP direct).
template<int MODE, bool SPARSE>
__global__ __launch_bounds__(256) void rowK(
    const float4* __restrict__ P1, const float4* __restrict__ P2,
    const float* __restrict__ stSr, const float* __restrict__ stTr,
    float* __restrict__ stSz, float* __restrict__ stTz,
    const float* __restrict__ remRr, float* __restrict__ remRw,
    float* __restrict__ stRS, float* __restrict__ stU,
    float* __restrict__ out,
    float coefP, float coefN)
{
    __shared__ float4 sCol[CH];                   // x2,y2,z2,remR_{j+1}
    __shared__ float  sPc[CH];                    // Pcol_j
    const int chunks = MM / CH;                   // 32
    const int bpb = (NN / 1024) * chunks;         // 64
    const int batch = blockIdx.x / bpb;
    const int rem   = blockIdx.x % bpb;
    const int rg    = rem / chunks;               // 0..1
    const int ic    = rem % chunks;
    const int t     = threadIdx.x;

    // prelude: finalize cols of this chunk (duplicated by 2 rg-blocks; identical values)
    float c = 0.0f;
    if (t < CH) {
        const int gl = batch * MM + ic * CH + t;
        const float R  = remRr[gl];
        const float s  = stSr[gl];
        const float t2 = stTr[gl];
        const float sumr = s * R;
        const float cons = fminf(R / (sumr + EPSF), 1.0f);
        const float pcol = R * cons;
        const float Rn   = fmaxf(R - sumr * cons, 0.0f);
        remRw[gl] = Rn;
        const float4 p = P2[gl];
        sCol[t] = make_float4(p.x, p.y, p.z, Rn);
        sPc[t]  = pcol;
        stSz[gl] = 0.0f; stTz[gl] = 0.0f;         // zero next accumulation parity
        if (rg == 0) c = pcol * t2;               // cost contribution (once per chunk)
    }
    if (rg == 0) {
#pragma unroll
        for (int off = 32; off > 0; off >>= 1) c += __shfl_xor(c, off, 64);
        if (t == 0) atomicAdd(out + batch, c);
    }
    __syncthreads();

    const int row0 = batch * NN + rg * 1024 + t;
    const float4 p0 = P1[row0];
    const float4 p1 = P1[row0 + 256];
    const float4 p2 = P1[row0 + 512];
    const float4 p3 = P1[row0 + 768];
    const v4f px = {p0.x, p1.x, p2.x, p3.x};
    const v4f py = {p0.y, p1.y, p2.y, p3.y};
    const v4f pz = {p0.z, p1.z, p2.z, p3.z};
    v4f rs = {0.0f, 0.0f, 0.0f, 0.0f}, u = {0.0f, 0.0f, 0.0f, 0.0f};
#pragma unroll 4
    for (int ii = 0; ii < CH; ++ii) {
        const float4 q = sCol[ii];
        const float pc = sPc[ii];
        const v4f dx = px - q.x, dy = py - q.y, dz = pz - q.z;
        const v4f d2 = dx*dx + dy*dy + dz*dz;
        if (MODE == 1) {
            const v4f g = coefN * d2;
            if (SPARSE) {
                const float gm = fmaxf(fmaxf(g.x, g.y), fmaxf(g.z, g.w));
                if (__ballot(gm > SKIPT)) {
                    v4f en;
                    en.x = __builtin_amdgcn_exp2f(g.x);
                    en.y = __builtin_amdgcn_exp2f(g.y);
                    en.z = __builtin_amdgcn_exp2f(g.z);
                    en.w = __builtin_amdgcn_exp2f(g.w);
                    const v4f e2 = en * en;
                    const v4f e4 = e2 * e2;
                    u  += e4 * pc;                // e_prev = e_next^4
                    rs += en * q.w;
                }
            } else {
                v4f en;
                en.x = __builtin_amdgcn_exp2f(g.x);
                en.y = __builtin_amdgcn_exp2f(g.y);
                en.z = __builtin_amdgcn_exp2f(g.z);
                en.w = __builtin_amdgcn_exp2f(g.w);
                const v4f e2 = en * en;
                const v4f e4 = e2 * e2;
                u  += e4 * pc;
                rs += en * q.w;
            }
        } else {
            const v4f g = coefP * d2;
            v4f ep;
            ep.x = __builtin_amdgcn_exp2f(g.x);
            ep.y = __builtin_amdgcn_exp2f(g.y);
            ep.z = __builtin_amdgcn_exp2f(g.z);
            ep.w = __builtin_amdgcn_exp2f(g.w);
            u  += ep * pc;
            rs += q.w;                            // e_next = exp(0) = 1
        }
    }
    atomicAdd(&stRS[row0],       rs.x);
    atomicAdd(&stU[row0],        u.x);
    atomicAdd(&stRS[row0 + 256], rs.y);
    atomicAdd(&stU[row0 + 256],  u.y);
    atomicAdd(&stRS[row0 + 512], rs.z);
    atomicAdd(&stU[row0 + 512],  u.z);
    atomicAdd(&stRS[row0 + 768], rs.w);
    atomicAdd(&stU[row0 + 768],  u.w);
}

// ---------------- finCost: cost for level 9 (no state updates) ----------------
__global__ __launch_bounds__(256) void finCost(
    const float* __restrict__ stSr, const float* __restrict__ stTr,
    const float* __restrict__ remRr, float* __restrict__ out)
{
    const int idx = blockIdx.x * 256 + threadIdx.x;
    const int batch = idx / MM;
    const float R = remRr[idx];
    const float sumr = stSr[idx] * R;
    const float cons = fminf(R / (sumr + EPSF), 1.0f);
    float c = R * cons * stTr[idx];
#pragma unroll
    for (int off = 32; off > 0; off >>= 1) c += __shfl_xor(c, off, 64);
    if ((threadIdx.x & 63) == 0) atomicAdd(out + batch, c);
}

extern "C" void kernel_launch(void* const* d_in, const int* in_sizes, int n_in,
                              void* d_out, int out_size, void* d_ws, size_t ws_size,
                              hipStream_t stream)
{
    const float* xyz1 = (const float*)d_in[0];
    const float* xyz2 = (const float*)d_in[1];
    float* out = (float*)d_out;

    const int BN = BB * NN, BM = BB * MM;
    float4* P1 = (float4*)d_ws;
    float4* P2 = P1 + BN;
    float* remL  = (float*)(P2 + BM);       // [2][BN]
    float* scale = remL + 2 * BN;           // [2][BN]
    float* remR  = scale + 2 * BN;          // [2][BM]
    float* stRS  = remR + 2 * BM;           // [2][BN]
    float* stU   = stRS + 2 * BN;           // [2][BN]
    float* stS   = stU + 2 * BN;            // [2][BM]
    float* stT   = stS + 2 * BM;            // [2][BM]

    init_kernel<<<dim3(BN / 256), dim3(256), 0, stream>>>(
        xyz1, xyz2, P1, P2, remR, stRS, stU, stS, stT, out);

    // levels: j = 7..-1 -> -(4^j), then 0.  coef = level * log2(e)
    float coef[10];
    const double lv[10] = {-16384.0, -4096.0, -1024.0, -256.0, -64.0,
                           -16.0, -4.0, -1.0, -0.25, 0.0};
    for (int i = 0; i < 10; ++i) coef[i] = (float)(lv[i] * 1.4426950408889634);

    dim3 grid(BB * 2 * (NN / CH));          // 16*2*32 = 1024
    dim3 fgrid(BM / 256);                   // 128
    dim3 blk(256);

    rowInit<<<grid, blk, 0, stream>>>(P1, P2, stRS + 1 * BN, coef[0]);

    for (int j = 0; j < 10; ++j) {
        const int p = j & 1, q = 1 - p;
        if (j == 0)
            colK<0, true><<<grid, blk, 0, stream>>>(P1, P2,
                stRS + q*BN, stU + q*BN, stRS + p*BN, stU + p*BN,
                remL + p*BN, remL + q*BN, scale + p*BN, scale + q*BN,
                stS + p*BM, stT + p*BM, coef[0]);
        else if (j <= 3)
            colK<1, true><<<grid, blk, 0, stream>>>(P1, P2,
                stRS + q*BN, stU + q*BN, stRS + p*BN, stU + p*BN,
                remL + p*BN, remL + q*BN, scale + p*BN, scale + q*BN,
                stS + p*BM, stT + p*BM, coef[j]);
        else if (j == 9)
            colK<2, false><<<grid, blk, 0, stream>>>(P1, P2,
                stRS + q*BN, stU + q*BN, stRS + p*BN, stU + p*BN,
                remL + p*BN, remL + q*BN, scale + p*BN, scale + q*BN,
                stS + p*BM, stT + p*BM, coef[9]);
        else
            colK<1, false><<<grid, blk, 0, stream>>>(P1, P2,
                stRS + q*BN, stU + q*BN, stRS + p*BN, stU + p*BN,
                remL + p*BN, remL + q*BN, scale + p*BN, scale + q*BN,
                stS + p*BM, stT + p*BM, coef[j]);

        if (j < 9) {
            if (j <= 2)
                rowK<1, true><<<grid, blk, 0, stream>>>(P1, P2,
                    stS + p*BM, stT + p*BM, stS + q*BM, stT + q*BM,
                    remR + p*BM, remR + q*BM,
                    stRS + p*BN, stU + p*BN, out, coef[j], coef[j+1]);
            else if (j < 8)
                rowK<1, false><<<grid, blk, 0, stream>>>(P1, P2,
                    stS + p*BM, stT + p*BM, stS + q*BM, stT + q*BM,
                    remR + p*BM, remR + q*BM,
                    stRS + p*BN, stU + p*BN, out, coef[j], coef[j+1]);
            else
                rowK<2, false><<<grid, blk, 0, stream>>>(P1, P2,
                    stS + p*BM, stT + p*BM, stS + q*BM, stT + q*BM,
                    remR + p*BM, remR + q*BM,
                    stRS + p*BN, stU + p*BN, out, coef[8], 0.0f);
        }
    }
    // level 9 cost: stS/stT parity 1, remR parity 1
    finCost<<<fgrid, blk, 0, stream>>>(stS + 1*BM, stT + 1*BM, remR + 1*BM, out);
}

// Round 4
// 491.346 us; speedup vs baseline: 5.0722x; 1.0622x over previous
//
#include <hip/hip_runtime.h>

#define BB 16
#define NN 2048
#define MM 2048
#define EPSF 1e-9f
#define SKIPT (-135.0f)   // exp2(arg) == 0 below this

typedef float v2f __attribute__((ext_vector_type(2)));
typedef float v4f __attribute__((ext_vector_type(4)));

constexpr int CH = 64;     // stream chunk length (4 outputs/thread)
// grid: BB batches x 2 groups(1024 own-points) x 32 chunks = 1024 blocks
// R0/R3 schedule+parity. Inner math forced to packed fp32 (v_pk_*) via
// inline asm; shared tiles stored DUPLICATED+NEGATED so broadcast operands
// are register pairs: sA=(-x,-x,-y,-y), sB=(-z,-z,s0,s1).

// ---- packed fp32 helpers (VOP3P; bit-identical IEEE to scalar ops) ----
__device__ __forceinline__ v2f pk_add(v2f a, v2f b){ v2f d; asm("v_pk_add_f32 %0, %1, %2" : "=v"(d) : "v"(a), "v"(b)); return d; }
__device__ __forceinline__ v2f pk_mul(v2f a, v2f b){ v2f d; asm("v_pk_mul_f32 %0, %1, %2" : "=v"(d) : "v"(a), "v"(b)); return d; }
__device__ __forceinline__ v2f pk_fma(v2f a, v2f b, v2f c){ v2f d; asm("v_pk_fma_f32 %0, %1, %2, %3" : "=v"(d) : "v"(a), "v"(b), "v"(c)); return d; }
__device__ __forceinline__ v2f lo2(v4f a){ return __builtin_shufflevector(a, a, 0, 1); }
__device__ __forceinline__ v2f hi2(v4f a){ return __builtin_shufflevector(a, a, 2, 3); }

// ---------------- init ----------------
__global__ __launch_bounds__(256) void init_kernel(
    const float* __restrict__ xyz1, const float* __restrict__ xyz2,
    float4* __restrict__ P1, float4* __restrict__ P2,
    float* __restrict__ remR0,
    float* __restrict__ stRS, float* __restrict__ stU,
    float* __restrict__ stS, float* __restrict__ stT,
    float* __restrict__ out)
{
    const int t = blockIdx.x * 256 + threadIdx.x;   // 0 .. BB*NN-1
    if (t < BB * NN) {
        P1[t] = make_float4(xyz1[3*t+0], xyz1[3*t+1], xyz1[3*t+2], 0.0f);
        stRS[t] = 0.0f; stRS[BB*NN + t] = 0.0f;
        stU[t]  = 0.0f; stU[BB*NN + t]  = 0.0f;
    }
    if (t < BB * MM) {
        P2[t] = make_float4(xyz2[3*t+0], xyz2[3*t+1], xyz2[3*t+2], 0.0f);
        remR0[t] = 1.0f;
        stS[t] = 0.0f; stS[BB*MM + t] = 0.0f;
        stT[t] = 0.0f; stT[BB*MM + t] = 0.0f;
    }
    if (t < BB) out[t] = 0.0f;
}

// ---------------- rowInit: stRS[1] += sum_l exp(coef0*d2) (remR=1) ----------------
__global__ __launch_bounds__(256) void rowInit(
    const float4* __restrict__ P1, const float4* __restrict__ P2,
    float* __restrict__ stRSacc, float coef)
{
    __shared__ v4f sA[CH], sB[CH];
    const int chunks = MM / CH;                   // 32
    const int bpb = (NN / 1024) * chunks;         // 64
    const int batch = blockIdx.x / bpb;
    const int rem   = blockIdx.x % bpb;
    const int rg    = rem / chunks;               // 0..1
    const int ic    = rem % chunks;
    const int t     = threadIdx.x;

    if (t < CH) {
        const float4 q = P2[batch * MM + ic * CH + t];
        sA[t] = (v4f){-q.x, -q.x, -q.y, -q.y};
        sB[t] = (v4f){-q.z, -q.z, 0.0f, 0.0f};
    }
    __syncthreads();

    const int row0 = batch * NN + rg * 1024 + t;
    const float4 p0 = P1[row0];
    const float4 p1 = P1[row0 + 256];
    const float4 p2 = P1[row0 + 512];
    const float4 p3 = P1[row0 + 768];
    const v2f pxL = {p0.x, p1.x}, pxH = {p2.x, p3.x};
    const v2f pyL = {p0.y, p1.y}, pyH = {p2.y, p3.y};
    const v2f pzL = {p0.z, p1.z}, pzH = {p2.z, p3.z};
    const v2f cf = {coef, coef};
    v2f rsL = {0.0f, 0.0f}, rsH = {0.0f, 0.0f};
#pragma unroll 4
    for (int ii = 0; ii < CH; ++ii) {
        const v4f A = sA[ii], B = sB[ii];
        const v2f nx = lo2(A), ny = hi2(A), nz = lo2(B);
        const v2f dxL = pk_add(pxL, nx), dxH = pk_add(pxH, nx);
        const v2f dyL = pk_add(pyL, ny), dyH = pk_add(pyH, ny);
        const v2f dzL = pk_add(pzL, nz), dzH = pk_add(pzH, nz);
        const v2f d2L = pk_fma(dxL, dxL, pk_fma(dyL, dyL, pk_mul(dzL, dzL)));
        const v2f d2H = pk_fma(dxH, dxH, pk_fma(dyH, dyH, pk_mul(dzH, dzH)));
        const v2f gL = pk_mul(d2L, cf), gH = pk_mul(d2H, cf);
        const float gm = fmaxf(fmaxf(gL.x, gL.y), fmaxf(gH.x, gH.y));
        if (__ballot(gm > SKIPT)) {
            v2f eL, eH;
            eL.x = __builtin_amdgcn_exp2f(gL.x); eL.y = __builtin_amdgcn_exp2f(gL.y);
            eH.x = __builtin_amdgcn_exp2f(gH.x); eH.y = __builtin_amdgcn_exp2f(gH.y);
            rsL = pk_add(rsL, eL);
            rsH = pk_add(rsH, eH);
        }
    }
    atomicAdd(&stRSacc[row0],       rsL.x);
    atomicAdd(&stRSacc[row0 + 256], rsL.y);
    atomicAdd(&stRSacc[row0 + 512], rsH.x);
    atomicAdd(&stRSacc[row0 + 768], rsH.y);
}

// ---------------- colK: row-finalize prelude + column-partial stream ----------------
// MODE 0: j==0 (remL=1). MODE 1: general. MODE 2: j==9 (coef==0 -> e=scale).
template<int MODE, bool SPARSE>
__global__ __launch_bounds__(256) void colK(
    const float4* __restrict__ P1, const float4* __restrict__ P2,
    const float* __restrict__ stRSr, const float* __restrict__ stUr,
    float* __restrict__ stRSz, float* __restrict__ stUz,
    const float* __restrict__ remLr, float* __restrict__ remLw,
    const float* __restrict__ scaler, float* __restrict__ scalew,
    float* __restrict__ stS, float* __restrict__ stT,
    float coef)
{
    __shared__ v4f sA[CH], sB[CH];                // (-x,-x,-y,-y), (-z,-z,sc,sc)
    const int chunks = NN / CH;                   // 32
    const int bpb = (MM / 1024) * chunks;         // 64
    const int batch = blockIdx.x / bpb;
    const int rem   = blockIdx.x % bpb;
    const int cg    = rem / chunks;               // 0..1
    const int ic    = rem % chunks;
    const int t     = threadIdx.x;

    // prelude: finalize rows of this chunk (duplicated by 2 cg-blocks; identical values)
    if (t < CH) {
        const int gi = batch * NN + ic * CH + t;
        float L;
        if (MODE == 0) L = 1.0f;
        else           L = fmaxf(remLr[gi] - scaler[gi] * stUr[gi], 0.0f);
        remLw[gi] = L;
        const float sc = L / (stRSr[gi] + EPSF);
        scalew[gi] = sc;
        const float4 p = P1[gi];
        sA[t] = (v4f){-p.x, -p.x, -p.y, -p.y};
        sB[t] = (v4f){-p.z, -p.z, sc, sc};
        stRSz[gi] = 0.0f; stUz[gi] = 0.0f;        // zero next accumulation parity
    }
    __syncthreads();

    const int col0 = batch * MM + cg * 1024 + t;
    const float4 q0 = P2[col0];
    const float4 q1 = P2[col0 + 256];
    const float4 q2 = P2[col0 + 512];
    const float4 q3 = P2[col0 + 768];
    const v2f qxL = {q0.x, q1.x}, qxH = {q2.x, q3.x};
    const v2f qyL = {q0.y, q1.y}, qyH = {q2.y, q3.y};
    const v2f qzL = {q0.z, q1.z}, qzH = {q2.z, q3.z};
    const v2f cf = {coef, coef};
    v2f sL = {0.0f, 0.0f}, sH = {0.0f, 0.0f};
    v2f ttL = {0.0f, 0.0f}, ttH = {0.0f, 0.0f};
#pragma unroll 4
    for (int ii = 0; ii < CH; ++ii) {
        const v4f A = sA[ii], B = sB[ii];
        const v2f nx = lo2(A), ny = hi2(A), nz = lo2(B), ss = hi2(B);
        const v2f dxL = pk_add(qxL, nx), dxH = pk_add(qxH, nx);
        const v2f dyL = pk_add(qyL, ny), dyH = pk_add(qyH, ny);
        const v2f dzL = pk_add(qzL, nz), dzH = pk_add(qzH, nz);
        const v2f d2L = pk_fma(dxL, dxL, pk_fma(dyL, dyL, pk_mul(dzL, dzL)));
        const v2f d2H = pk_fma(dxH, dxH, pk_fma(dyH, dyH, pk_mul(dzH, dzH)));
        if (SPARSE) {
            const v2f gL = pk_mul(d2L, cf), gH = pk_mul(d2H, cf);
            const float gm = fmaxf(fmaxf(gL.x, gL.y), fmaxf(gH.x, gH.y));
            if (__ballot(gm > SKIPT)) {
                v2f eL, eH;
                eL.x = __builtin_amdgcn_exp2f(gL.x); eL.y = __builtin_amdgcn_exp2f(gL.y);
                eH.x = __builtin_amdgcn_exp2f(gH.x); eH.y = __builtin_amdgcn_exp2f(gH.y);
                eL = pk_mul(eL, ss); eH = pk_mul(eH, ss);
                v2f sqL, sqH;
                sqL.x = __builtin_amdgcn_sqrtf(d2L.x); sqL.y = __builtin_amdgcn_sqrtf(d2L.y);
                sqH.x = __builtin_amdgcn_sqrtf(d2H.x); sqH.y = __builtin_amdgcn_sqrtf(d2H.y);
                sL = pk_add(sL, eL); sH = pk_add(sH, eH);
                ttL = pk_fma(eL, sqL, ttL); ttH = pk_fma(eH, sqH, ttH);
            }
        } else {
            v2f eL, eH;
            if (MODE == 2) { eL = ss; eH = ss; }
            else {
                const v2f gL = pk_mul(d2L, cf), gH = pk_mul(d2H, cf);
                eL.x = __builtin_amdgcn_exp2f(gL.x); eL.y = __builtin_amdgcn_exp2f(gL.y);
                eH.x = __builtin_amdgcn_exp2f(gH.x); eH.y = __builtin_amdgcn_exp2f(gH.y);
                eL = pk_mul(eL, ss); eH = pk_mul(eH, ss);
            }
            v2f sqL, sqH;
            sqL.x = __builtin_amdgcn_sqrtf(d2L.x); sqL.y = __builtin_amdgcn_sqrtf(d2L.y);
            sqH.x = __builtin_amdgcn_sqrtf(d2H.x); sqH.y = __builtin_amdgcn_sqrtf(d2H.y);
            sL = pk_add(sL, eL); sH = pk_add(sH, eH);
            ttL = pk_fma(eL, sqL, ttL); ttH = pk_fma(eH, sqH, ttH);
        }
    }
    atomicAdd(&stS[col0],       sL.x);
    atomicAdd(&stT[col0],       ttL.x);
    atomicAdd(&stS[col0 + 256], sL.y);
    atomicAdd(&stT[col0 + 256], ttL.y);
    atomicAdd(&stS[col0 + 512], sH.x);
    atomicAdd(&stT[col0 + 512], ttH.x);
    atomicAdd(&stS[col0 + 768], sH.y);
    atomicAdd(&stT[col0 + 768], ttH.y);
}

// ---------------- rowK: col-finalize prelude + row-partial stream ----------------
// MODE 1: general. MODE 2: j==8 (rs = sum remR_9, u at coefP direct).
template<int MODE, bool SPARSE>
__global__ __launch_bounds__(256) void rowK(
    const float4* __restrict__ P1, const float4* __restrict__ P2,
    const float* __restrict__ stSr, const float* __restrict__ stTr,
    float* __restrict__ stSz, float* __restrict__ stTz,
    const float* __restrict__ remRr, float* __restrict__ remRw,
    float* __restrict__ stRS, float* __restrict__ stU,
    float* __restrict__ out,
    float coefP, float coefN)
{
    __shared__ v4f sA[CH], sB[CH];                // (-x,-x,-y,-y), (-z,-z,Rn,pc)
    const int chunks = MM / CH;                   // 32
    const int bpb = (NN / 1024) * chunks;         // 64
    const int batch = blockIdx.x / bpb;
    const int rem   = blockIdx.x % bpb;
    const int rg    = rem / chunks;               // 0..1
    const int ic    = rem % chunks;
    const int t     = threadIdx.x;

    // prelude: finalize cols of this chunk (duplicated by 2 rg-blocks; identical values)
    float c = 0.0f;
    if (t < CH) {
        const int gl = batch * MM + ic * CH + t;
        const float R  = remRr[gl];
        const float s  = stSr[gl];
        const float t2 = stTr[gl];
        const float sumr = s * R;
        const float cons = fminf(R / (sumr + EPSF), 1.0f);
        const float pcol = R * cons;
        const float Rn   = fmaxf(R - sumr * cons, 0.0f);
        remRw[gl] = Rn;
        const float4 p = P2[gl];
        sA[t] = (v4f){-p.x, -p.x, -p.y, -p.y};
        sB[t] = (v4f){-p.z, -p.z, Rn, pcol};
        stSz[gl] = 0.0f; stTz[gl] = 0.0f;         // zero next accumulation parity
        if (rg == 0) c = pcol * t2;               // cost contribution (once per chunk)
    }
    if (rg == 0) {
#pragma unroll
        for (int off = 32; off > 0; off >>= 1) c += __shfl_xor(c, off, 64);
        if (t == 0) atomicAdd(out + batch, c);
    }
    __syncthreads();

    const int row0 = batch * NN + rg * 1024 + t;
    const float4 p0 = P1[row0];
    const float4 p1 = P1[row0 + 256];
    const float4 p2 = P1[row0 + 512];
    const float4 p3 = P1[row0 + 768];
    const v2f pxL = {p0.x, p1.x}, pxH = {p2.x, p3.x};
    const v2f pyL = {p0.y, p1.y}, pyH = {p2.y, p3.y};
    const v2f pzL = {p0.z, p1.z}, pzH = {p2.z, p3.z};
    const v2f cfN = {coefN, coefN};
    const v2f cfP = {coefP, coefP};
    v2f rsL = {0.0f, 0.0f}, rsH = {0.0f, 0.0f};
    v2f uL  = {0.0f, 0.0f}, uH  = {0.0f, 0.0f};
#pragma unroll 4
    for (int ii = 0; ii < CH; ++ii) {
        const v4f A = sA[ii], B = sB[ii];
        const v2f nx = lo2(A), ny = hi2(A), nz = lo2(B);
        const float Rn = B.z, pc = B.w;
        const v2f dxL = pk_add(pxL, nx), dxH = pk_add(pxH, nx);
        const v2f dyL = pk_add(pyL, ny), dyH = pk_add(pyH, ny);
        const v2f dzL = pk_add(pzL, nz), dzH = pk_add(pzH, nz);
        const v2f d2L = pk_fma(dxL, dxL, pk_fma(dyL, dyL, pk_mul(dzL, dzL)));
        const v2f d2H = pk_fma(dxH, dxH, pk_fma(dyH, dyH, pk_mul(dzH, dzH)));
        if (MODE == 1) {
            const v2f gL = pk_mul(d2L, cfN), gH = pk_mul(d2H, cfN);
            bool go = true;
            if (SPARSE) {
                const float gm = fmaxf(fmaxf(gL.x, gL.y), fmaxf(gH.x, gH.y));
                go = __ballot(gm > SKIPT) != 0ull;
            }
            if (go) {
                v2f enL, enH;
                enL.x = __builtin_amdgcn_exp2f(gL.x); enL.y = __builtin_amdgcn_exp2f(gL.y);
                enH.x = __builtin_amdgcn_exp2f(gH.x); enH.y = __builtin_amdgcn_exp2f(gH.y);
                const v2f e2L = pk_mul(enL, enL), e2H = pk_mul(enH, enH);
                const v2f e4L = pk_mul(e2L, e2L), e4H = pk_mul(e2H, e2H);
                uL.x = fmaf(e4L.x, pc, uL.x); uL.y = fmaf(e4L.y, pc, uL.y);
                uH.x = fmaf(e4H.x, pc, uH.x); uH.y = fmaf(e4H.y, pc, uH.y);
                rsL.x = fmaf(enL.x, Rn, rsL.x); rsL.y = fmaf(enL.y, Rn, rsL.y);
                rsH.x = fmaf(enH.x, Rn, rsH.x); rsH.y = fmaf(enH.y, Rn, rsH.y);
            }
        } else {
            const v2f gL = pk_mul(d2L, cfP), gH = pk_mul(d2H, cfP);
            v2f epL, epH;
            epL.x = __builtin_amdgcn_exp2f(gL.x); epL.y = __builtin_amdgcn_exp2f(gL.y);
            epH.x = __builtin_amdgcn_exp2f(gH.x); epH.y = __builtin_amdgcn_exp2f(gH.y);
            uL.x = fmaf(epL.x, pc, uL.x); uL.y = fmaf(epL.y, pc, uL.y);
            uH.x = fmaf(epH.x, pc, uH.x); uH.y = fmaf(epH.y, pc, uH.y);
            rsL.x += Rn; rsL.y += Rn;             // e_next = exp(0) = 1
            rsH.x += Rn; rsH.y += Rn;
        }
    }
    atomicAdd(&stRS[row0],       rsL.x);
    atomicAdd(&stU[row0],        uL.x);
    atomicAdd(&stRS[row0 + 256], rsL.y);
    atomicAdd(&stU[row0 + 256],  uL.y);
    atomicAdd(&stRS[row0 + 512], rsH.x);
    atomicAdd(&stU[row0 + 512],  uH.x);
    atomicAdd(&stRS[row0 + 768], rsH.y);
    atomicAdd(&stU[row0 + 768],  uH.y);
}

// ---------------- finCost: cost for level 9 (no state updates) ----------------
__global__ __launch_bounds__(256) void finCost(
    const float* __restrict__ stSr, const float* __restrict__ stTr,
    const float* __restrict__ remRr, float* __restrict__ out)
{
    const int idx = blockIdx.x * 256 + threadIdx.x;
    const int batch = idx / MM;
    const float R = remRr[idx];
    const float sumr = stSr[idx] * R;
    const float cons = fminf(R / (sumr + EPSF), 1.0f);
    float c = R * cons * stTr[idx];
#pragma unroll
    for (int off = 32; off > 0; off >>= 1) c += __shfl_xor(c, off, 64);
    if ((threadIdx.x & 63) == 0) atomicAdd(out + batch, c);
}

extern "C" void kernel_launch(void* const* d_in, const int* in_sizes, int n_in,
                              void* d_out, int out_size, void* d_ws, size_t ws_size,
                              hipStream_t stream)
{
    const float* xyz1 = (const float*)d_in[0];
    const float* xyz2 = (const float*)d_in[1];
    float* out = (float*)d_out;

    const int BN = BB * NN, BM = BB * MM;
    float4* P1 = (float4*)d_ws;
    float4* P2 = P1 + BN;
    float* remL  = (float*)(P2 + BM);       // [2][BN]
    float* scale = remL + 2 * BN;           // [2][BN]
    float* remR  = scale + 2 * BN;          // [2][BM]
    float* stRS  = remR + 2 * BM;           // [2][BN]
    float* stU   = stRS + 2 * BN;           // [2][BN]
    float* stS   = stU + 2 * BN;            // [2][BM]
    float* stT   = stS + 2 * BM;            // [2][BM]

    init_kernel<<<dim3(BN / 256), dim3(256), 0, stream>>>(
        xyz1, xyz2, P1, P2, remR, stRS, stU, stS, stT, out);

    // levels: j = 7..-1 -> -(4^j), then 0.  coef = level * log2(e)
    float coef[10];
    const double lv[10] = {-16384.0, -4096.0, -1024.0, -256.0, -64.0,
                           -16.0, -4.0, -1.0, -0.25, 0.0};
    for (int i = 0; i < 10; ++i) coef[i] = (float)(lv[i] * 1.4426950408889634);

    dim3 grid(BB * 2 * (NN / CH));          // 16*2*32 = 1024
    dim3 fgrid(BM / 256);                   // 128
    dim3 blk(256);

    rowInit<<<grid, blk, 0, stream>>>(P1, P2, stRS + 1 * BN, coef[0]);

    for (int j = 0; j < 10; ++j) {
        const int p = j & 1, q = 1 - p;
        if (j == 0)
            colK<0, true><<<grid, blk, 0, stream>>>(P1, P2,
                stRS + q*BN, stU + q*BN, stRS + p*BN, stU + p*BN,
                remL + p*BN, remL + q*BN, scale + p*BN, scale + q*BN,
                stS + p*BM, stT + p*BM, coef[0]);
        else if (j <= 3)
            colK<1, true><<<grid, blk, 0, stream>>>(P1, P2,
                stRS + q*BN, stU + q*BN, stRS + p*BN, stU + p*BN,
                remL + p*BN, remL + q*BN, scale + p*BN, scale + q*BN,
                stS + p*BM, stT + p*BM, coef[j]);
        else if (j == 9)
            colK<2, false><<<grid, blk, 0, stream>>>(P1, P2,
                stRS + q*BN, stU + q*BN, stRS + p*BN, stU + p*BN,
                remL + p*BN, remL + q*BN, scale + p*BN, scale + q*BN,
                stS + p*BM, stT + p*BM, coef[9]);
        else
            colK<1, false><<<grid, blk, 0, stream>>>(P1, P2,
                stRS + q*BN, stU + q*BN, stRS + p*BN, stU + p*BN,
                remL + p*BN, remL + q*BN, scale + p*BN, scale + q*BN,
                stS + p*BM, stT + p*BM, coef[j]);

        if (j < 9) {
            if (j <= 2)
                rowK<1, true><<<grid, blk, 0, stream>>>(P1, P2,
                    stS + p*BM, stT + p*BM, stS + q*BM, stT + q*BM,
                    remR + p*BM, remR + q*BM,
                    stRS + p*BN, stU + p*BN, out, coef[j], coef[j+1]);
            else if (j < 8)
                rowK<1, false><<<grid, blk, 0, stream>>>(P1, P2,
                    stS + p*BM, stT + p*BM, stS + q*BM, stT + q*BM,
                    remR + p*BM, remR + q*BM,
                    stRS + p*BN, stU + p*BN, out, coef[j], coef[j+1]);
            else
                rowK<2, false><<<grid, blk, 0, stream>>>(P1, P2,
                    stS + p*BM, stT + p*BM, stS + q*BM, stT + q*BM,
                    remR + p*BM, remR + q*BM,
                    stRS + p*BN, stU + p*BN, out, coef[8], 0.0f);
        }
    }
    // level 9 cost: stS/stT parity 1, remR parity 1
    finCost<<<fgrid, blk, 0, stream>>>(stS + 1*BM, stT + 1*BM, remR + 1*BM, out);
}

// Round 6
// 462.572 us; speedup vs baseline: 5.3877x; 1.0622x over previous
//
#include <hip/hip_runtime.h>

#define BB 16
#define NN 2048
#define MM 2048
#define EPSF 1e-9f
#define SKIPT (-135.0f)   // exp2(arg) == 0 below this

typedef float v2f __attribute__((ext_vector_type(2)));
typedef float v4f __attribute__((ext_vector_type(4)));

constexpr int CH = 64;     // stream chunk length (2 outputs/thread)
// grid: BB batches x 4 groups(512 own-points) x 32 chunks = 2048 blocks
// (8 blocks/CU natural occupancy; NO forced launch_bounds min-waves --
//  R5 showed (256,8)+CH=32 miscompiles/races with the pk-asm body.)
// R0 geometry + R4 packed-fp32 math. LDS tiles duplicated+negated:
// sA=(-x,-x,-y,-y), sB=(-z,-z,s0,s1) so pk broadcast operands are pairs.

// ---- packed fp32 helpers (VOP3P; same IEEE ops as scalar) ----
__device__ __forceinline__ v2f pk_add(v2f a, v2f b){ v2f d; asm("v_pk_add_f32 %0, %1, %2" : "=v"(d) : "v"(a), "v"(b)); return d; }
__device__ __forceinline__ v2f pk_mul(v2f a, v2f b){ v2f d; asm("v_pk_mul_f32 %0, %1, %2" : "=v"(d) : "v"(a), "v"(b)); return d; }
__device__ __forceinline__ v2f pk_fma(v2f a, v2f b, v2f c){ v2f d; asm("v_pk_fma_f32 %0, %1, %2, %3" : "=v"(d) : "v"(a), "v"(b), "v"(c)); return d; }
__device__ __forceinline__ v2f lo2(v4f a){ return __builtin_shufflevector(a, a, 0, 1); }
__device__ __forceinline__ v2f hi2(v4f a){ return __builtin_shufflevector(a, a, 2, 3); }

// ---------------- init ----------------
__global__ __launch_bounds__(256) void init_kernel(
    const float* __restrict__ xyz1, const float* __restrict__ xyz2,
    float4* __restrict__ P1, float4* __restrict__ P2,
    float* __restrict__ remR0,
    float* __restrict__ stRS, float* __restrict__ stU,
    float* __restrict__ stS, float* __restrict__ stT,
    float* __restrict__ out)
{
    const int t = blockIdx.x * 256 + threadIdx.x;   // 0 .. BB*NN-1
    if (t < BB * NN) {
        P1[t] = make_float4(xyz1[3*t+0], xyz1[3*t+1], xyz1[3*t+2], 0.0f);
        stRS[t] = 0.0f; stRS[BB*NN + t] = 0.0f;
        stU[t]  = 0.0f; stU[BB*NN + t]  = 0.0f;
    }
    if (t < BB * MM) {
        P2[t] = make_float4(xyz2[3*t+0], xyz2[3*t+1], xyz2[3*t+2], 0.0f);
        remR0[t] = 1.0f;
        stS[t] = 0.0f; stS[BB*MM + t] = 0.0f;
        stT[t] = 0.0f; stT[BB*MM + t] = 0.0f;
    }
    if (t < BB) out[t] = 0.0f;
}

// ---------------- rowInit: stRS[1] += sum_l exp(coef0*d2) (remR=1) ----------------
__global__ __launch_bounds__(256) void rowInit(
    const float4* __restrict__ P1, const float4* __restrict__ P2,
    float* __restrict__ stRSacc, float coef)
{
    __shared__ v4f sA[CH], sB[CH];
    const int chunks = MM / CH;                   // 32
    const int bpb = (NN / 512) * chunks;          // 128
    const int batch = blockIdx.x / bpb;
    const int rem   = blockIdx.x % bpb;
    const int rg    = rem / chunks;               // 0..3
    const int ic    = rem % chunks;
    const int t     = threadIdx.x;

    if (t < CH) {
        const float4 q = P2[batch * MM + ic * CH + t];
        sA[t] = (v4f){-q.x, -q.x, -q.y, -q.y};
        sB[t] = (v4f){-q.z, -q.z, 0.0f, 0.0f};
    }
    __syncthreads();

    const int row0 = batch * NN + rg * 512 + t;
    const int row1 = row0 + 256;
    const float4 p0 = P1[row0];
    const float4 p1 = P1[row1];
    const v2f px = {p0.x, p1.x}, py = {p0.y, p1.y}, pz = {p0.z, p1.z};
    const v2f cf = {coef, coef};
    v2f rs = {0.0f, 0.0f};
#pragma unroll 4
    for (int ii = 0; ii < CH; ++ii) {
        const v4f A = sA[ii], B = sB[ii];
        const v2f nx = lo2(A), ny = hi2(A), nz = lo2(B);
        const v2f dx = pk_add(px, nx);
        const v2f dy = pk_add(py, ny);
        const v2f dz = pk_add(pz, nz);
        const v2f d2 = pk_fma(dx, dx, pk_fma(dy, dy, pk_mul(dz, dz)));
        const v2f g = pk_mul(d2, cf);
        if (__ballot(fmaxf(g.x, g.y) > SKIPT)) {
            v2f e;
            e.x = __builtin_amdgcn_exp2f(g.x);
            e.y = __builtin_amdgcn_exp2f(g.y);
            rs = pk_add(rs, e);
        }
    }
    atomicAdd(&stRSacc[row0], rs.x);
    atomicAdd(&stRSacc[row1], rs.y);
}

// ---------------- colK: row-finalize prelude + column-partial stream ----------------
// MODE 0: j==0 (remL=1). MODE 1: general. MODE 2: j==9 (coef==0 -> e=scale).
template<int MODE, bool SPARSE>
__global__ __launch_bounds__(256) void colK(
    const float4* __restrict__ P1, const float4* __restrict__ P2,
    const float* __restrict__ stRSr, const float* __restrict__ stUr,
    float* __restrict__ stRSz, float* __restrict__ stUz,
    const float* __restrict__ remLr, float* __restrict__ remLw,
    const float* __restrict__ scaler, float* __restrict__ scalew,
    float* __restrict__ stS, float* __restrict__ stT,
    float coef)
{
    __shared__ v4f sA[CH], sB[CH];                // (-x,-x,-y,-y), (-z,-z,sc,sc)
    const int chunks = NN / CH;                   // 32
    const int bpb = (MM / 512) * chunks;          // 128
    const int batch = blockIdx.x / bpb;
    const int rem   = blockIdx.x % bpb;
    const int cg    = rem / chunks;               // 0..3
    const int ic    = rem % chunks;
    const int t     = threadIdx.x;

    // prelude: finalize rows of this chunk (duplicated by 4 cg-blocks; identical values)
    if (t < CH) {
        const int gi = batch * NN + ic * CH + t;
        float L;
        if (MODE == 0) L = 1.0f;
        else           L = fmaxf(remLr[gi] - scaler[gi] * stUr[gi], 0.0f);
        remLw[gi] = L;
        const float sc = L / (stRSr[gi] + EPSF);
        scalew[gi] = sc;
        const float4 p = P1[gi];
        sA[t] = (v4f){-p.x, -p.x, -p.y, -p.y};
        sB[t] = (v4f){-p.z, -p.z, sc, sc};
        stRSz[gi] = 0.0f; stUz[gi] = 0.0f;        // zero next accumulation parity
    }
    __syncthreads();

    const int col0 = batch * MM + cg * 512 + t;
    const int col1 = col0 + 256;
    const float4 q0 = P2[col0];
    const float4 q1 = P2[col1];
    const v2f qx = {q0.x, q1.x}, qy = {q0.y, q1.y}, qz = {q0.z, q1.z};
    const v2f cf = {coef, coef};
    v2f s = {0.0f, 0.0f}, tt = {0.0f, 0.0f};
#pragma unroll 4
    for (int ii = 0; ii < CH; ++ii) {
        const v4f A = sA[ii], B = sB[ii];
        const v2f nx = lo2(A), ny = hi2(A), nz = lo2(B), ss = hi2(B);
        const v2f dx = pk_add(qx, nx);
        const v2f dy = pk_add(qy, ny);
        const v2f dz = pk_add(qz, nz);
        const v2f d2 = pk_fma(dx, dx, pk_fma(dy, dy, pk_mul(dz, dz)));
        if (SPARSE) {
            const v2f g = pk_mul(d2, cf);
            if (__ballot(fmaxf(g.x, g.y) > SKIPT)) {
                v2f e;
                e.x = __builtin_amdgcn_exp2f(g.x);
                e.y = __builtin_amdgcn_exp2f(g.y);
                e = pk_mul(e, ss);
                v2f sq;
                sq.x = __builtin_amdgcn_sqrtf(d2.x);
                sq.y = __builtin_amdgcn_sqrtf(d2.y);
                s = pk_add(s, e);
                tt = pk_fma(e, sq, tt);
            }
        } else {
            v2f e;
            if (MODE == 2) { e = ss; }
            else {
                const v2f g = pk_mul(d2, cf);
                e.x = __builtin_amdgcn_exp2f(g.x);
                e.y = __builtin_amdgcn_exp2f(g.y);
                e = pk_mul(e, ss);
            }
            v2f sq;
            sq.x = __builtin_amdgcn_sqrtf(d2.x);
            sq.y = __builtin_amdgcn_sqrtf(d2.y);
            s = pk_add(s, e);
            tt = pk_fma(e, sq, tt);
        }
    }
    atomicAdd(&stS[col0], s.x);
    atomicAdd(&stT[col0], tt.x);
    atomicAdd(&stS[col1], s.y);
    atomicAdd(&stT[col1], tt.y);
}

// ---------------- rowK: col-finalize prelude + row-partial stream ----------------
// MODE 1: general. MODE 2: j==8 (rs = sum remR_9, u at coefP direct).
template<int MODE, bool SPARSE>
__global__ __launch_bounds__(256) void rowK(
    const float4* __restrict__ P1, const float4* __restrict__ P2,
    const float* __restrict__ stSr, const float* __restrict__ stTr,
    float* __restrict__ stSz, float* __restrict__ stTz,
    const float* __restrict__ remRr, float* __restrict__ remRw,
    float* __restrict__ stRS, float* __restrict__ stU,
    float* __restrict__ out,
    float coefP, float coefN)
{
    __shared__ v4f sA[CH], sB[CH];                // (-x,-x,-y,-y), (-z,-z,Rn,pc)
    const int chunks = MM / CH;                   // 32
    const int bpb = (NN / 512) * chunks;          // 128
    const int batch = blockIdx.x / bpb;
    const int rem   = blockIdx.x % bpb;
    const int rg    = rem / chunks;               // 0..3
    const int ic    = rem % chunks;
    const int t     = threadIdx.x;

    // prelude: finalize cols of this chunk (duplicated by 4 rg-blocks; identical values)
    float c = 0.0f;
    if (t < CH) {
        const int gl = batch * MM + ic * CH + t;
        const float R  = remRr[gl];
        const float s  = stSr[gl];
        const float t2 = stTr[gl];
        const float sumr = s * R;
        const float cons = fminf(R / (sumr + EPSF), 1.0f);
        const float pcol = R * cons;
        const float Rn   = fmaxf(R - sumr * cons, 0.0f);
        remRw[gl] = Rn;
        const float4 p = P2[gl];
        sA[t] = (v4f){-p.x, -p.x, -p.y, -p.y};
        sB[t] = (v4f){-p.z, -p.z, Rn, pcol};
        stSz[gl] = 0.0f; stTz[gl] = 0.0f;         // zero next accumulation parity
        if (rg == 0) c = pcol * t2;               // cost contribution (once per chunk)
    }
    if (rg == 0) {
#pragma unroll
        for (int off = 32; off > 0; off >>= 1) c += __shfl_xor(c, off, 64);
        if (t == 0) atomicAdd(out + batch, c);
    }
    __syncthreads();

    const int row0 = batch * NN + rg * 512 + t;
    const int row1 = row0 + 256;
    const float4 p0 = P1[row0];
    const float4 p1 = P1[row1];
    const v2f px = {p0.x, p1.x}, py = {p0.y, p1.y}, pz = {p0.z, p1.z};
    const v2f cfN = {coefN, coefN};
    const v2f cfP = {coefP, coefP};
    v2f rs = {0.0f, 0.0f}, u = {0.0f, 0.0f};
#pragma unroll 4
    for (int ii = 0; ii < CH; ++ii) {
        const v4f A = sA[ii], B = sB[ii];
        const v2f nx = lo2(A), ny = hi2(A), nz = lo2(B);
        const float Rn = B.z, pc = B.w;
        const v2f dx = pk_add(px, nx);
        const v2f dy = pk_add(py, ny);
        const v2f dz = pk_add(pz, nz);
        const v2f d2 = pk_fma(dx, dx, pk_fma(dy, dy, pk_mul(dz, dz)));
        if (MODE == 1) {
            const v2f g = pk_mul(d2, cfN);
            bool go = true;
            if (SPARSE) go = __ballot(fmaxf(g.x, g.y) > SKIPT) != 0ull;
            if (go) {
                v2f en;
                en.x = __builtin_amdgcn_exp2f(g.x);
                en.y = __builtin_amdgcn_exp2f(g.y);
                const v2f e2 = pk_mul(en, en);
                const v2f e4 = pk_mul(e2, e2);
                u.x = fmaf(e4.x, pc, u.x);  u.y = fmaf(e4.y, pc, u.y);
                rs.x = fmaf(en.x, Rn, rs.x); rs.y = fmaf(en.y, Rn, rs.y);
            }
        } else {
            const v2f g = pk_mul(d2, cfP);
            v2f ep;
            ep.x = __builtin_amdgcn_exp2f(g.x);
            ep.y = __builtin_amdgcn_exp2f(g.y);
            u.x = fmaf(ep.x, pc, u.x);  u.y = fmaf(ep.y, pc, u.y);
            rs.x += Rn; rs.y += Rn;               // e_next = exp(0) = 1
        }
    }
    atomicAdd(&stRS[row0], rs.x);
    atomicAdd(&stU[row0],  u.x);
    atomicAdd(&stRS[row1], rs.y);
    atomicAdd(&stU[row1],  u.y);
}

// ---------------- finCost: cost for level 9 (no state updates) ----------------
__global__ __launch_bounds__(256) void finCost(
    const float* __restrict__ stSr, const float* __restrict__ stTr,
    const float* __restrict__ remRr, float* __restrict__ out)
{
    const int idx = blockIdx.x * 256 + threadIdx.x;
    const int batch = idx / MM;
    const float R = remRr[idx];
    const float sumr = stSr[idx] * R;
    const float cons = fminf(R / (sumr + EPSF), 1.0f);
    float c = R * cons * stTr[idx];
#pragma unroll
    for (int off = 32; off > 0; off >>= 1) c += __shfl_xor(c, off, 64);
    if ((threadIdx.x & 63) == 0) atomicAdd(out + batch, c);
}

extern "C" void kernel_launch(void* const* d_in, const int* in_sizes, int n_in,
                              void* d_out, int out_size, void* d_ws, size_t ws_size,
                              hipStream_t stream)
{
    const float* xyz1 = (const float*)d_in[0];
    const float* xyz2 = (const float*)d_in[1];
    float* out = (float*)d_out;

    const int BN = BB * NN, BM = BB * MM;
    float4* P1 = (float4*)d_ws;
    float4* P2 = P1 + BN;
    float* remL  = (float*)(P2 + BM);       // [2][BN]
    float* scale = remL + 2 * BN;           // [2][BN]
    float* remR  = scale + 2 * BN;          // [2][BM]
    float* stRS  = remR + 2 * BM;           // [2][BN]
    float* stU   = stRS + 2 * BN;           // [2][BN]
    float* stS   = stU + 2 * BN;            // [2][BM]
    float* stT   = stS + 2 * BM;            // [2][BM]

    init_kernel<<<dim3(BN / 256), dim3(256), 0, stream>>>(
        xyz1, xyz2, P1, P2, remR, stRS, stU, stS, stT, out);

    // levels: j = 7..-1 -> -(4^j), then 0.  coef = level * log2(e)
    float coef[10];
    const double lv[10] = {-16384.0, -4096.0, -1024.0, -256.0, -64.0,
                           -16.0, -4.0, -1.0, -0.25, 0.0};
    for (int i = 0; i < 10; ++i) coef[i] = (float)(lv[i] * 1.4426950408889634);

    dim3 grid(BB * 4 * (NN / CH));          // 16*4*32 = 2048 (8 blocks/CU)
    dim3 fgrid(BM / 256);                   // 128
    dim3 blk(256);

    rowInit<<<grid, blk, 0, stream>>>(P1, P2, stRS + 1 * BN, coef[0]);

    for (int j = 0; j < 10; ++j) {
        const int p = j & 1, q = 1 - p;
        if (j == 0)
            colK<0, true><<<grid, blk, 0, stream>>>(P1, P2,
                stRS + q*BN, stU + q*BN, stRS + p*BN, stU + p*BN,
                remL + p*BN, remL + q*BN, scale + p*BN, scale + q*BN,
                stS + p*BM, stT + p*BM, coef[0]);
        else if (j <= 3)
            colK<1, true><<<grid, blk, 0, stream>>>(P1, P2,
                stRS + q*BN, stU + q*BN, stRS + p*BN, stU + p*BN,
                remL + p*BN, remL + q*BN, scale + p*BN, scale + q*BN,
                stS + p*BM, stT + p*BM, coef[j]);
        else if (j == 9)
            colK<2, false><<<grid, blk, 0, stream>>>(P1, P2,
                stRS + q*BN, stU + q*BN, stRS + p*BN, stU + p*BN,
                remL + p*BN, remL + q*BN, scale + p*BN, scale + q*BN,
                stS + p*BM, stT + p*BM, coef[9]);
        else
            colK<1, false><<<grid, blk, 0, stream>>>(P1, P2,
                stRS + q*BN, stU + q*BN, stRS + p*BN, stU + p*BN,
                remL + p*BN, remL + q*BN, scale + p*BN, scale + q*BN,
                stS + p*BM, stT + p*BM, coef[j]);

        if (j < 9) {
            if (j <= 2)
                rowK<1, true><<<grid, blk, 0, stream>>>(P1, P2,
                    stS + p*BM, stT + p*BM, stS + q*BM, stT + q*BM,
                    remR + p*BM, remR + q*BM,
                    stRS + p*BN, stU + p*BN, out, coef[j], coef[j+1]);
            else if (j < 8)
                rowK<1, false><<<grid, blk, 0, stream>>>(P1, P2,
                    stS + p*BM, stT + p*BM, stS + q*BM, stT + q*BM,
                    remR + p*BM, remR + q*BM,
                    stRS + p*BN, stU + p*BN, out, coef[j], coef[j+1]);
            else
                rowK<2, false><<<grid, blk, 0, stream>>>(P1, P2,
                    stS + p*BM, stT + p*BM, stS + q*BM, stT + q*BM,
                    remR + p*BM, remR + q*BM,
                    stRS + p*BN, stU + p*BN, out, coef[8], 0.0f);
        }
    }
    // level 9 cost: stS/stT parity 1, remR parity 1
    finCost<<<fgrid, blk, 0, stream>>>(stS + 1*BM, stT + 1*BM, remR + 1*BM, out);
}

// Round 9
// 456.911 us; speedup vs baseline: 5.4544x; 1.0124x over previous
//
#include <hip/hip_runtime.h>

#define BB 16
#define NN 2048
#define MM 2048
#define EPSF 1e-9f
#define SKIPT (-135.0f)   // exp2(arg) == 0 below this

typedef float v2f __attribute__((ext_vector_type(2)));
typedef float v4f __attribute__((ext_vector_type(4)));

constexpr int CH = 64;     // stream chunk length (2 outputs/thread)
// grid: BB batches x 4 groups(512 own-points) x 32 chunks = 2048 blocks
// R9: pair-packed tiles -- pk lanes hold TWO TILE POINTS:
//   tA[k] = {-x_{2k}, -x_{2k+1}, -y_{2k}, -y_{2k+1}}
//   tB[k] = {-z_{2k}, -z_{2k+1},  w_{2k},  w_{2k+1}}   (w = sc / Rn)
// Own-point coords are duplicated into pairs once outside the loop.
// Tiles are written as WHOLE v4f stores by CH/2 repack threads (no
// float*-cast scatter -- R8's only unverified mechanism); per-point
// scalars staged through a plain float LDS array. Math uses only the
// plain v_pk_* helpers verified in R4/R6 (no op_sel -- R7 failure).

// ---- packed fp32 helpers (VOP3P; verified R4/R6) ----
__device__ __forceinline__ v2f pk_add(v2f a, v2f b){ v2f d; asm("v_pk_add_f32 %0, %1, %2" : "=v"(d) : "v"(a), "v"(b)); return d; }
__device__ __forceinline__ v2f pk_mul(v2f a, v2f b){ v2f d; asm("v_pk_mul_f32 %0, %1, %2" : "=v"(d) : "v"(a), "v"(b)); return d; }
__device__ __forceinline__ v2f pk_fma(v2f a, v2f b, v2f c){ v2f d; asm("v_pk_fma_f32 %0, %1, %2, %3" : "=v"(d) : "v"(a), "v"(b), "v"(c)); return d; }
__device__ __forceinline__ v2f lo2(v4f a){ return __builtin_shufflevector(a, a, 0, 1); }
__device__ __forceinline__ v2f hi2(v4f a){ return __builtin_shufflevector(a, a, 2, 3); }

// ---------------- init ----------------
__global__ __launch_bounds__(256) void init_kernel(
    const float* __restrict__ xyz1, const float* __restrict__ xyz2,
    float4* __restrict__ P1, float4* __restrict__ P2,
    float* __restrict__ remR0,
    float* __restrict__ stRS, float* __restrict__ stU,
    float* __restrict__ stS, float* __restrict__ stT,
    float* __restrict__ out)
{
    const int t = blockIdx.x * 256 + threadIdx.x;   // 0 .. BB*NN-1
    if (t < BB * NN) {
        P1[t] = make_float4(xyz1[3*t+0], xyz1[3*t+1], xyz1[3*t+2], 0.0f);
        stRS[t] = 0.0f; stRS[BB*NN + t] = 0.0f;
        stU[t]  = 0.0f; stU[BB*NN + t]  = 0.0f;
    }
    if (t < BB * MM) {
        P2[t] = make_float4(xyz2[3*t+0], xyz2[3*t+1], xyz2[3*t+2], 0.0f);
        remR0[t] = 1.0f;
        stS[t] = 0.0f; stS[BB*MM + t] = 0.0f;
        stT[t] = 0.0f; stT[BB*MM + t] = 0.0f;
    }
    if (t < BB) out[t] = 0.0f;
}

// ---------------- rowInit: stRS[1] += sum_l exp(coef0*d2) (remR=1) ----------------
__global__ __launch_bounds__(256) void rowInit(
    const float4* __restrict__ P1, const float4* __restrict__ P2,
    float* __restrict__ stRSacc, float coef)
{
    __shared__ v4f tA[CH / 2];                    // {-x0,-x1,-y0,-y1}
    __shared__ v2f tZ[CH / 2];                    // {-z0,-z1}
    const int chunks = MM / CH;                   // 32
    const int bpb = (NN / 512) * chunks;          // 128
    const int batch = blockIdx.x / bpb;
    const int rem   = blockIdx.x % bpb;
    const int rg    = rem / chunks;               // 0..3
    const int ic    = rem % chunks;
    const int t     = threadIdx.x;

    if (t < CH / 2) {
        const int gi = batch * MM + ic * CH + 2 * t;
        const float4 a = P2[gi];
        const float4 b = P2[gi + 1];
        tA[t] = (v4f){-a.x, -b.x, -a.y, -b.y};
        tZ[t] = (v2f){-a.z, -b.z};
    }
    __syncthreads();

    const int row0 = batch * NN + rg * 512 + t;
    const int row1 = row0 + 256;
    const float4 p0 = P1[row0];
    const float4 p1 = P1[row1];
    const v2f ax0 = {p0.x, p0.x}, ay0 = {p0.y, p0.y}, az0 = {p0.z, p0.z};
    const v2f ax1 = {p1.x, p1.x}, ay1 = {p1.y, p1.y}, az1 = {p1.z, p1.z};
    const v2f cf = {coef, coef};
    v2f rs0 = {0.0f, 0.0f}, rs1 = {0.0f, 0.0f};
#pragma unroll 4
    for (int k = 0; k < CH / 2; ++k) {
        const v4f A = tA[k];
        const v2f Zn = tZ[k];
        const v2f Xn = lo2(A), Yn = hi2(A);
        const v2f dx0 = pk_add(Xn, ax0), dy0 = pk_add(Yn, ay0), dz0 = pk_add(Zn, az0);
        const v2f d20 = pk_fma(dx0, dx0, pk_fma(dy0, dy0, pk_mul(dz0, dz0)));
        const v2f dx1 = pk_add(Xn, ax1), dy1 = pk_add(Yn, ay1), dz1 = pk_add(Zn, az1);
        const v2f d21 = pk_fma(dx1, dx1, pk_fma(dy1, dy1, pk_mul(dz1, dz1)));
        const v2f g0 = pk_mul(d20, cf), g1 = pk_mul(d21, cf);
        const float gm = fmaxf(fmaxf(g0.x, g0.y), fmaxf(g1.x, g1.y));
        if (__ballot(gm > SKIPT)) {
            v2f e0, e1;
            e0.x = __builtin_amdgcn_exp2f(g0.x); e0.y = __builtin_amdgcn_exp2f(g0.y);
            e1.x = __builtin_amdgcn_exp2f(g1.x); e1.y = __builtin_amdgcn_exp2f(g1.y);
            rs0 = pk_add(rs0, e0);
            rs1 = pk_add(rs1, e1);
        }
    }
    atomicAdd(&stRSacc[row0], rs0.x + rs0.y);
    atomicAdd(&stRSacc[row1], rs1.x + rs1.y);
}

// ---------------- colK: row-finalize prelude + column-partial stream ----------------
// MODE 0: j==0 (remL=1). MODE 1: general. MODE 2: j==9 (coef==0 -> e=scale).
template<int MODE, bool SPARSE>
__global__ __launch_bounds__(256) void colK(
    const float4* __restrict__ P1, const float4* __restrict__ P2,
    const float* __restrict__ stRSr, const float* __restrict__ stUr,
    float* __restrict__ stRSz, float* __restrict__ stUz,
    const float* __restrict__ remLr, float* __restrict__ remLw,
    const float* __restrict__ scaler, float* __restrict__ scalew,
    float* __restrict__ stS, float* __restrict__ stT,
    float coef)
{
    __shared__ v4f tA[CH / 2];                    // {-x0,-x1,-y0,-y1}  (P1 rows)
    __shared__ v4f tB[CH / 2];                    // {-z0,-z1, sc0, sc1}
    __shared__ float sSc[CH];
    const int chunks = NN / CH;                   // 32
    const int bpb = (MM / 512) * chunks;          // 128
    const int batch = blockIdx.x / bpb;
    const int rem   = blockIdx.x % bpb;
    const int cg    = rem / chunks;               // 0..3
    const int ic    = rem % chunks;
    const int t     = threadIdx.x;

    // prelude: finalize rows of this chunk (duplicated by 4 cg-blocks; identical values)
    if (t < CH) {
        const int gi = batch * NN + ic * CH + t;
        float L;
        if (MODE == 0) L = 1.0f;
        else           L = fmaxf(remLr[gi] - scaler[gi] * stUr[gi], 0.0f);
        remLw[gi] = L;
        const float sc = L / (stRSr[gi] + EPSF);
        scalew[gi] = sc;
        sSc[t] = sc;
        stRSz[gi] = 0.0f; stUz[gi] = 0.0f;        // zero next accumulation parity
    }
    __syncthreads();
    if (t < CH / 2) {
        const int gi = batch * NN + ic * CH + 2 * t;
        const float4 a = P1[gi];
        const float4 b = P1[gi + 1];
        tA[t] = (v4f){-a.x, -b.x, -a.y, -b.y};
        tB[t] = (v4f){-a.z, -b.z, sSc[2*t], sSc[2*t + 1]};
    }
    __syncthreads();

    const int col0 = batch * MM + cg * 512 + t;
    const int col1 = col0 + 256;
    const float4 q0 = P2[col0];
    const float4 q1 = P2[col1];
    const v2f ax0 = {q0.x, q0.x}, ay0 = {q0.y, q0.y}, az0 = {q0.z, q0.z};
    const v2f ax1 = {q1.x, q1.x}, ay1 = {q1.y, q1.y}, az1 = {q1.z, q1.z};
    const v2f cf = {coef, coef};
    v2f s0 = {0.0f, 0.0f}, s1 = {0.0f, 0.0f};
    v2f tt0 = {0.0f, 0.0f}, tt1 = {0.0f, 0.0f};
#pragma unroll 4
    for (int k = 0; k < CH / 2; ++k) {
        const v4f A = tA[k], B = tB[k];
        const v2f Xn = lo2(A), Yn = hi2(A), Zn = lo2(B), Wsc = hi2(B);
        const v2f dx0 = pk_add(Xn, ax0), dy0 = pk_add(Yn, ay0), dz0 = pk_add(Zn, az0);
        const v2f d20 = pk_fma(dx0, dx0, pk_fma(dy0, dy0, pk_mul(dz0, dz0)));
        const v2f dx1 = pk_add(Xn, ax1), dy1 = pk_add(Yn, ay1), dz1 = pk_add(Zn, az1);
        const v2f d21 = pk_fma(dx1, dx1, pk_fma(dy1, dy1, pk_mul(dz1, dz1)));
        if (SPARSE) {
            const v2f g0 = pk_mul(d20, cf), g1 = pk_mul(d21, cf);
            const float gm = fmaxf(fmaxf(g0.x, g0.y), fmaxf(g1.x, g1.y));
            if (__ballot(gm > SKIPT)) {
                v2f e0, e1, sq0, sq1;
                e0.x = __builtin_amdgcn_exp2f(g0.x); e0.y = __builtin_amdgcn_exp2f(g0.y);
                e1.x = __builtin_amdgcn_exp2f(g1.x); e1.y = __builtin_amdgcn_exp2f(g1.y);
                e0 = pk_mul(e0, Wsc);
                e1 = pk_mul(e1, Wsc);
                sq0.x = __builtin_amdgcn_sqrtf(d20.x); sq0.y = __builtin_amdgcn_sqrtf(d20.y);
                sq1.x = __builtin_amdgcn_sqrtf(d21.x); sq1.y = __builtin_amdgcn_sqrtf(d21.y);
                s0 = pk_add(s0, e0);  tt0 = pk_fma(e0, sq0, tt0);
                s1 = pk_add(s1, e1);  tt1 = pk_fma(e1, sq1, tt1);
            }
        } else {
            v2f e0, e1, sq0, sq1;
            if (MODE == 2) { e0 = Wsc; e1 = Wsc; }
            else {
                const v2f g0 = pk_mul(d20, cf), g1 = pk_mul(d21, cf);
                e0.x = __builtin_amdgcn_exp2f(g0.x); e0.y = __builtin_amdgcn_exp2f(g0.y);
                e1.x = __builtin_amdgcn_exp2f(g1.x); e1.y = __builtin_amdgcn_exp2f(g1.y);
                e0 = pk_mul(e0, Wsc);
                e1 = pk_mul(e1, Wsc);
            }
            sq0.x = __builtin_amdgcn_sqrtf(d20.x); sq0.y = __builtin_amdgcn_sqrtf(d20.y);
            sq1.x = __builtin_amdgcn_sqrtf(d21.x); sq1.y = __builtin_amdgcn_sqrtf(d21.y);
            s0 = pk_add(s0, e0);  tt0 = pk_fma(e0, sq0, tt0);
            s1 = pk_add(s1, e1);  tt1 = pk_fma(e1, sq1, tt1);
        }
    }
    atomicAdd(&stS[col0], s0.x + s0.y);
    atomicAdd(&stT[col0], tt0.x + tt0.y);
    atomicAdd(&stS[col1], s1.x + s1.y);
    atomicAdd(&stT[col1], tt1.x + tt1.y);
}

// ---------------- rowK: col-finalize prelude + row-partial stream ----------------
// MODE 1: general. MODE 2: j==8 (rs = sum remR_9, u at coefP direct).
template<int MODE, bool SPARSE>
__global__ __launch_bounds__(256) void rowK(
    const float4* __restrict__ P1, const float4* __restrict__ P2,
    const float* __restrict__ stSr, const float* __restrict__ stTr,
    float* __restrict__ stSz, float* __restrict__ stTz,
    const float* __restrict__ remRr, float* __restrict__ remRw,
    float* __restrict__ stRS, float* __restrict__ stU,
    float* __restrict__ out,
    float coefP, float coefN)
{
    __shared__ v4f tA[CH / 2];                    // {-x0,-x1,-y0,-y1}  (P2 cols)
    __shared__ v4f tB[CH / 2];                    // {-z0,-z1, Rn0, Rn1}
    __shared__ v2f tC[CH / 2];                    // {pc0, pc1}
    __shared__ float sRn[CH], sPcs[CH];
    const int chunks = MM / CH;                   // 32
    const int bpb = (NN / 512) * chunks;          // 128
    const int batch = blockIdx.x / bpb;
    const int rem   = blockIdx.x % bpb;
    const int rg    = rem / chunks;               // 0..3
    const int ic    = rem % chunks;
    const int t     = threadIdx.x;

    // prelude: finalize cols of this chunk (duplicated by 4 rg-blocks; identical values)
    float c = 0.0f;
    if (t < CH) {
        const int gl = batch * MM + ic * CH + t;
        const float R  = remRr[gl];
        const float s  = stSr[gl];
        const float t2 = stTr[gl];
        const float sumr = s * R;
        const float cons = fminf(R / (sumr + EPSF), 1.0f);
        const float pcol = R * cons;
        const float Rn   = fmaxf(R - sumr * cons, 0.0f);
        remRw[gl] = Rn;
        sRn[t]  = Rn;
        sPcs[t] = pcol;
        stSz[gl] = 0.0f; stTz[gl] = 0.0f;         // zero next accumulation parity
        if (rg == 0) c = pcol * t2;               // cost contribution (once per chunk)
    }
    if (rg == 0) {
#pragma unroll
        for (int off = 32; off > 0; off >>= 1) c += __shfl_xor(c, off, 64);
        if (t == 0) atomicAdd(out + batch, c);
    }
    __syncthreads();
    if (t < CH / 2) {
        const int gl = batch * MM + ic * CH + 2 * t;
        const float4 a = P2[gl];
        const float4 b = P2[gl + 1];
        tA[t] = (v4f){-a.x, -b.x, -a.y, -b.y};
        tB[t] = (v4f){-a.z, -b.z, sRn[2*t], sRn[2*t + 1]};
        tC[t] = (v2f){sPcs[2*t], sPcs[2*t + 1]};
    }
    __syncthreads();

    const int row0 = batch * NN + rg * 512 + t;
    const int row1 = row0 + 256;
    const float4 p0 = P1[row0];
    const float4 p1 = P1[row1];
    const v2f ax0 = {p0.x, p0.x}, ay0 = {p0.y, p0.y}, az0 = {p0.z, p0.z};
    const v2f ax1 = {p1.x, p1.x}, ay1 = {p1.y, p1.y}, az1 = {p1.z, p1.z};
    const v2f cfN = {coefN, coefN};
    const v2f cfP = {coefP, coefP};
    v2f rs0 = {0.0f, 0.0f}, rs1 = {0.0f, 0.0f};
    v2f u0  = {0.0f, 0.0f}, u1  = {0.0f, 0.0f};
#pragma unroll 4
    for (int k = 0; k < CH / 2; ++k) {
        const v4f A = tA[k], B = tB[k];
        const v2f Pc = tC[k];
        const v2f Xn = lo2(A), Yn = hi2(A), Zn = lo2(B), Rnp = hi2(B);
        const v2f dx0 = pk_add(Xn, ax0), dy0 = pk_add(Yn, ay0), dz0 = pk_add(Zn, az0);
        const v2f d20 = pk_fma(dx0, dx0, pk_fma(dy0, dy0, pk_mul(dz0, dz0)));
        const v2f dx1 = pk_add(Xn, ax1), dy1 = pk_add(Yn, ay1), dz1 = pk_add(Zn, az1);
        const v2f d21 = pk_fma(dx1, dx1, pk_fma(dy1, dy1, pk_mul(dz1, dz1)));
        if (MODE == 1) {
            const v2f g0 = pk_mul(d20, cfN), g1 = pk_mul(d21, cfN);
            bool go = true;
            if (SPARSE) {
                const float gm = fmaxf(fmaxf(g0.x, g0.y), fmaxf(g1.x, g1.y));
                go = __ballot(gm > SKIPT) != 0ull;
            }
            if (go) {
                v2f en0, en1;
                en0.x = __builtin_amdgcn_exp2f(g0.x); en0.y = __builtin_amdgcn_exp2f(g0.y);
                en1.x = __builtin_amdgcn_exp2f(g1.x); en1.y = __builtin_amdgcn_exp2f(g1.y);
                const v2f e20 = pk_mul(en0, en0), e21 = pk_mul(en1, en1);
                const v2f e40 = pk_mul(e20, e20), e41 = pk_mul(e21, e21);
                u0  = pk_fma(e40, Pc, u0);
                u1  = pk_fma(e41, Pc, u1);
                rs0 = pk_fma(en0, Rnp, rs0);
                rs1 = pk_fma(en1, Rnp, rs1);
            }
        } else {
            const v2f g0 = pk_mul(d20, cfP), g1 = pk_mul(d21, cfP);
            v2f ep0, ep1;
            ep0.x = __builtin_amdgcn_exp2f(g0.x); ep0.y = __builtin_amdgcn_exp2f(g0.y);
            ep1.x = __builtin_amdgcn_exp2f(g1.x); ep1.y = __builtin_amdgcn_exp2f(g1.y);
            u0  = pk_fma(ep0, Pc, u0);
            u1  = pk_fma(ep1, Pc, u1);
            rs0 = pk_add(rs0, Rnp);               // e_next = exp(0) = 1
            rs1 = pk_add(rs1, Rnp);
        }
    }
    atomicAdd(&stRS[row0], rs0.x + rs0.y);
    atomicAdd(&stU[row0],  u0.x + u0.y);
    atomicAdd(&stRS[row1], rs1.x + rs1.y);
    atomicAdd(&stU[row1],  u1.x + u1.y);
}

// ---------------- finCost: cost for level 9 (no state updates) ----------------
__global__ __launch_bounds__(256) void finCost(
    const float* __restrict__ stSr, const float* __restrict__ stTr,
    const float* __restrict__ remRr, float* __restrict__ out)
{
    const int idx = blockIdx.x * 256 + threadIdx.x;
    const int batch = idx / MM;
    const float R = remRr[idx];
    const float sumr = stSr[idx] * R;
    const float cons = fminf(R / (sumr + EPSF), 1.0f);
    float c = R * cons * stTr[idx];
#pragma unroll
    for (int off = 32; off > 0; off >>= 1) c += __shfl_xor(c, off, 64);
    if ((threadIdx.x & 63) == 0) atomicAdd(out + batch, c);
}

extern "C" void kernel_launch(void* const* d_in, const int* in_sizes, int n_in,
                              void* d_out, int out_size, void* d_ws, size_t ws_size,
                              hipStream_t stream)
{
    const float* xyz1 = (const float*)d_in[0];
    const float* xyz2 = (const float*)d_in[1];
    float* out = (float*)d_out;

    const int BN = BB * NN, BM = BB * MM;
    float4* P1 = (float4*)d_ws;
    float4* P2 = P1 + BN;
    float* remL  = (float*)(P2 + BM);       // [2][BN]
    float* scale = remL + 2 * BN;           // [2][BN]
    float* remR  = scale + 2 * BN;          // [2][BM]
    float* stRS  = remR + 2 * BM;           // [2][BN]
    float* stU   = stRS + 2 * BN;           // [2][BN]
    float* stS   = stU + 2 * BN;            // [2][BM]
    float* stT   = stS + 2 * BM;            // [2][BM]

    init_kernel<<<dim3(BN / 256), dim3(256), 0, stream>>>(
        xyz1, xyz2, P1, P2, remR, stRS, stU, stS, stT, out);

    // levels: j = 7..-1 -> -(4^j), then 0.  coef = level * log2(e)
    float coef[10];
    const double lv[10] = {-16384.0, -4096.0, -1024.0, -256.0, -64.0,
                           -16.0, -4.0, -1.0, -0.25, 0.0};
    for (int i = 0; i < 10; ++i) coef[i] = (float)(lv[i] * 1.4426950408889634);

    dim3 grid(BB * 4 * (NN / CH));          // 16*4*32 = 2048 (8 blocks/CU)
    dim3 fgrid(BM / 256);                   // 128
    dim3 blk(256);

    rowInit<<<grid, blk, 0, stream>>>(P1, P2, stRS + 1 * BN, coef[0]);

    for (int j = 0; j < 10; ++j) {
        const int p = j & 1, q = 1 - p;
        if (j == 0)
            colK<0, true><<<grid, blk, 0, stream>>>(P1, P2,
                stRS + q*BN, stU + q*BN, stRS + p*BN, stU + p*BN,
                remL + p*BN, remL + q*BN, scale + p*BN, scale + q*BN,
                stS + p*BM, stT + p*BM, coef[0]);
        else if (j <= 3)
            colK<1, true><<<grid, blk, 0, stream>>>(P1, P2,
                stRS + q*BN, stU + q*BN, stRS + p*BN, stU + p*BN,
                remL + p*BN, remL + q*BN, scale + p*BN, scale + q*BN,
                stS + p*BM, stT + p*BM, coef[j]);
        else if (j == 9)
            colK<2, false><<<grid, blk, 0, stream>>>(P1, P2,
                stRS + q*BN, stU + q*BN, stRS + p*BN, stU + p*BN,
                remL + p*BN, remL + q*BN, scale + p*BN, scale + q*BN,
                stS + p*BM, stT + p*BM, coef[9]);
        else
            colK<1, false><<<grid, blk, 0, stream>>>(P1, P2,
                stRS + q*BN, stU + q*BN, stRS + p*BN, stU + p*BN,
                remL + p*BN, remL + q*BN, scale + p*BN, scale + q*BN,
                stS + p*BM, stT + p*BM, coef[j]);

        if (j < 9) {
            if (j <= 2)
                rowK<1, true><<<grid, blk, 0, stream>>>(P1, P2,
                    stS + p*BM, stT + p*BM, stS + q*BM, stT + q*BM,
                    remR + p*BM, remR + q*BM,
                    stRS + p*BN, stU + p*BN, out, coef[j], coef[j+1]);
            else if (j < 8)
                rowK<1, false><<<grid, blk, 0, stream>>>(P1, P2,
                    stS + p*BM, stT + p*BM, stS + q*BM, stT + q*BM,
                    remR + p*BM, remR + q*BM,
                    stRS + p*BN, stU + p*BN, out, coef[j], coef[j+1]);
            else
                rowK<2, false><<<grid, blk, 0, stream>>>(P1, P2,
                    stS + p*BM, stT + p*BM, stS + q*BM, stT + q*BM,
                    remR + p*BM, remR + q*BM,
                    stRS + p*BN, stU + p*BN, out, coef[8], 0.0f);
        }
    }
    // level 9 cost: stS/stT parity 1, remR parity 1
    finCost<<<fgrid, blk, 0, stream>>>(stS + 1*BM, stT + 1*BM, remR + 1*BM, out);
}

// Round 11
// 450.663 us; speedup vs baseline: 5.5301x; 1.0139x over previous
//
#include <hip/hip_runtime.h>

#define BB 16
#define NN 2048
#define MM 2048
#define EPSF 1e-9f
#define SKIPT (-135.0f)   // exp2(arg) == 0 below this

typedef float v2f __attribute__((ext_vector_type(2)));
typedef float v4f __attribute__((ext_vector_type(4)));

constexpr int CH = 64;     // stream chunk length (2 outputs/thread)
// R11: R9 body at 512 threads/block. grid = BB x 2 halves x 32 chunks =
// 1024 blocks (2 prelude duplications per chunk, was 4). launch_bounds(512)
// keeps VGPR cap at 256 -- no spill pressure (R5/R10 failures are attributed
// to VGPR-cap-induced spilling of inline-asm v2f pairs at caps 64/128).
// Independent global loads hoisted above the prelude; both barriers kept.

// ---- packed fp32 helpers (VOP3P; verified R4/R6/R9) ----
__device__ __forceinline__ v2f pk_add(v2f a, v2f b){ v2f d; asm("v_pk_add_f32 %0, %1, %2" : "=v"(d) : "v"(a), "v"(b)); return d; }
__device__ __forceinline__ v2f pk_mul(v2f a, v2f b){ v2f d; asm("v_pk_mul_f32 %0, %1, %2" : "=v"(d) : "v"(a), "v"(b)); return d; }
__device__ __forceinline__ v2f pk_fma(v2f a, v2f b, v2f c){ v2f d; asm("v_pk_fma_f32 %0, %1, %2, %3" : "=v"(d) : "v"(a), "v"(b), "v"(c)); return d; }
__device__ __forceinline__ v2f lo2(v4f a){ return __builtin_shufflevector(a, a, 0, 1); }
__device__ __forceinline__ v2f hi2(v4f a){ return __builtin_shufflevector(a, a, 2, 3); }

// ---------------- init ----------------
__global__ __launch_bounds__(256) void init_kernel(
    const float* __restrict__ xyz1, const float* __restrict__ xyz2,
    float4* __restrict__ P1, float4* __restrict__ P2,
    float* __restrict__ remR0,
    float* __restrict__ stRS, float* __restrict__ stU,
    float* __restrict__ stS, float* __restrict__ stT,
    float* __restrict__ out)
{
    const int t = blockIdx.x * 256 + threadIdx.x;   // 0 .. BB*NN-1
    if (t < BB * NN) {
        P1[t] = make_float4(xyz1[3*t+0], xyz1[3*t+1], xyz1[3*t+2], 0.0f);
        stRS[t] = 0.0f; stRS[BB*NN + t] = 0.0f;
        stU[t]  = 0.0f; stU[BB*NN + t]  = 0.0f;
    }
    if (t < BB * MM) {
        P2[t] = make_float4(xyz2[3*t+0], xyz2[3*t+1], xyz2[3*t+2], 0.0f);
        remR0[t] = 1.0f;
        stS[t] = 0.0f; stS[BB*MM + t] = 0.0f;
        stT[t] = 0.0f; stT[BB*MM + t] = 0.0f;
    }
    if (t < BB) out[t] = 0.0f;
}

// ---------------- rowInit: stRS[1] += sum_l exp(coef0*d2) (remR=1) ----------------
__global__ __launch_bounds__(512) void rowInit(
    const float4* __restrict__ P1, const float4* __restrict__ P2,
    float* __restrict__ stRSacc, float coef)
{
    __shared__ v4f tA[CH / 2];                    // {-x0,-x1,-y0,-y1}
    __shared__ v2f tZ[CH / 2];                    // {-z0,-z1}
    const int chunks = MM / CH;                   // 32
    const int bpb = (NN / 1024) * chunks;         // 64
    const int batch = blockIdx.x / bpb;
    const int rem   = blockIdx.x % bpb;
    const int rg    = rem / chunks;               // 0..1
    const int ic    = rem % chunks;
    const int t     = threadIdx.x;                // 0..511

    const int row0 = batch * NN + rg * 1024 + t;
    const int row1 = row0 + 512;
    const float4 p0 = P1[row0];                   // hoisted: in flight during staging
    const float4 p1 = P1[row1];

    if (t < CH / 2) {
        const int gi = batch * MM + ic * CH + 2 * t;
        const float4 a = P2[gi];
        const float4 b = P2[gi + 1];
        tA[t] = (v4f){-a.x, -b.x, -a.y, -b.y};
        tZ[t] = (v2f){-a.z, -b.z};
    }
    __syncthreads();

    const v2f ax0 = {p0.x, p0.x}, ay0 = {p0.y, p0.y}, az0 = {p0.z, p0.z};
    const v2f ax1 = {p1.x, p1.x}, ay1 = {p1.y, p1.y}, az1 = {p1.z, p1.z};
    const v2f cf = {coef, coef};
    v2f rs0 = {0.0f, 0.0f}, rs1 = {0.0f, 0.0f};
#pragma unroll 4
    for (int k = 0; k < CH / 2; ++k) {
        const v4f A = tA[k];
        const v2f Zn = tZ[k];
        const v2f Xn = lo2(A), Yn = hi2(A);
        const v2f dx0 = pk_add(Xn, ax0), dy0 = pk_add(Yn, ay0), dz0 = pk_add(Zn, az0);
        const v2f d20 = pk_fma(dx0, dx0, pk_fma(dy0, dy0, pk_mul(dz0, dz0)));
        const v2f dx1 = pk_add(Xn, ax1), dy1 = pk_add(Yn, ay1), dz1 = pk_add(Zn, az1);
        const v2f d21 = pk_fma(dx1, dx1, pk_fma(dy1, dy1, pk_mul(dz1, dz1)));
        const v2f g0 = pk_mul(d20, cf), g1 = pk_mul(d21, cf);
        const float gm = fmaxf(fmaxf(g0.x, g0.y), fmaxf(g1.x, g1.y));
        if (__ballot(gm > SKIPT)) {
            v2f e0, e1;
            e0.x = __builtin_amdgcn_exp2f(g0.x); e0.y = __builtin_amdgcn_exp2f(g0.y);
            e1.x = __builtin_amdgcn_exp2f(g1.x); e1.y = __builtin_amdgcn_exp2f(g1.y);
            rs0 = pk_add(rs0, e0);
            rs1 = pk_add(rs1, e1);
        }
    }
    atomicAdd(&stRSacc[row0], rs0.x + rs0.y);
    atomicAdd(&stRSacc[row1], rs1.x + rs1.y);
}

// ---------------- colK: row-finalize prelude + column-partial stream ----------------
// MODE 0: j==0 (remL=1). MODE 1: general. MODE 2: j==9 (coef==0 -> e=scale).
template<int MODE, bool SPARSE>
__global__ __launch_bounds__(512) void colK(
    const float4* __restrict__ P1, const float4* __restrict__ P2,
    const float* __restrict__ stRSr, const float* __restrict__ stUr,
    float* __restrict__ stRSz, float* __restrict__ stUz,
    const float* __restrict__ remLr, float* __restrict__ remLw,
    const float* __restrict__ scaler, float* __restrict__ scalew,
    float* __restrict__ stS, float* __restrict__ stT,
    float coef)
{
    __shared__ v4f tA[CH / 2];                    // {-x0,-x1,-y0,-y1}  (P1 rows)
    __shared__ v4f tB[CH / 2];                    // {-z0,-z1, sc0, sc1}
    __shared__ float sSc[CH];
    const int chunks = NN / CH;                   // 32
    const int bpb = (MM / 1024) * chunks;         // 64
    const int batch = blockIdx.x / bpb;
    const int rem   = blockIdx.x % bpb;
    const int cg    = rem / chunks;               // 0..1
    const int ic    = rem % chunks;
    const int t     = threadIdx.x;                // 0..511

    const int col0 = batch * MM + cg * 1024 + t;
    const int col1 = col0 + 512;
    const float4 q0 = P2[col0];                   // hoisted above prelude
    const float4 q1 = P2[col1];
    float4 a, b;
    if (t < CH / 2) {                             // hoisted staging loads
        const int gi2 = batch * NN + ic * CH + 2 * t;
        a = P1[gi2];
        b = P1[gi2 + 1];
    }

    // prelude: finalize rows of this chunk (duplicated by 2 cg-blocks; identical values)
    if (t < CH) {
        const int gi = batch * NN + ic * CH + t;
        float L;
        if (MODE == 0) L = 1.0f;
        else           L = fmaxf(remLr[gi] - scaler[gi] * stUr[gi], 0.0f);
        remLw[gi] = L;
        const float sc = L / (stRSr[gi] + EPSF);
        scalew[gi] = sc;
        sSc[t] = sc;
        stRSz[gi] = 0.0f; stUz[gi] = 0.0f;        // zero next accumulation parity
    }
    __syncthreads();
    if (t < CH / 2) {
        tA[t] = (v4f){-a.x, -b.x, -a.y, -b.y};
        tB[t] = (v4f){-a.z, -b.z, sSc[2*t], sSc[2*t + 1]};
    }
    __syncthreads();

    const v2f ax0 = {q0.x, q0.x}, ay0 = {q0.y, q0.y}, az0 = {q0.z, q0.z};
    const v2f ax1 = {q1.x, q1.x}, ay1 = {q1.y, q1.y}, az1 = {q1.z, q1.z};
    const v2f cf = {coef, coef};
    v2f s0 = {0.0f, 0.0f}, s1 = {0.0f, 0.0f};
    v2f tt0 = {0.0f, 0.0f}, tt1 = {0.0f, 0.0f};
#pragma unroll 4
    for (int k = 0; k < CH / 2; ++k) {
        const v4f A = tA[k], B = tB[k];
        const v2f Xn = lo2(A), Yn = hi2(A), Zn = lo2(B), Wsc = hi2(B);
        const v2f dx0 = pk_add(Xn, ax0), dy0 = pk_add(Yn, ay0), dz0 = pk_add(Zn, az0);
        const v2f d20 = pk_fma(dx0, dx0, pk_fma(dy0, dy0, pk_mul(dz0, dz0)));
        const v2f dx1 = pk_add(Xn, ax1), dy1 = pk_add(Yn, ay1), dz1 = pk_add(Zn, az1);
        const v2f d21 = pk_fma(dx1, dx1, pk_fma(dy1, dy1, pk_mul(dz1, dz1)));
        if (SPARSE) {
            const v2f g0 = pk_mul(d20, cf), g1 = pk_mul(d21, cf);
            const float gm = fmaxf(fmaxf(g0.x, g0.y), fmaxf(g1.x, g1.y));
            if (__ballot(gm > SKIPT)) {
                v2f e0, e1, sq0, sq1;
                e0.x = __builtin_amdgcn_exp2f(g0.x); e0.y = __builtin_amdgcn_exp2f(g0.y);
                e1.x = __builtin_amdgcn_exp2f(g1.x); e1.y = __builtin_amdgcn_exp2f(g1.y);
                e0 = pk_mul(e0, Wsc);
                e1 = pk_mul(e1, Wsc);
                sq0.x = __builtin_amdgcn_sqrtf(d20.x); sq0.y = __builtin_amdgcn_sqrtf(d20.y);
                sq1.x = __builtin_amdgcn_sqrtf(d21.x); sq1.y = __builtin_amdgcn_sqrtf(d21.y);
                s0 = pk_add(s0, e0);  tt0 = pk_fma(e0, sq0, tt0);
                s1 = pk_add(s1, e1);  tt1 = pk_fma(e1, sq1, tt1);
            }
        } else {
            v2f e0, e1, sq0, sq1;
            if (MODE == 2) { e0 = Wsc; e1 = Wsc; }
            else {
                const v2f g0 = pk_mul(d20, cf), g1 = pk_mul(d21, cf);
                e0.x = __builtin_amdgcn_exp2f(g0.x); e0.y = __builtin_amdgcn_exp2f(g0.y);
                e1.x = __builtin_amdgcn_exp2f(g1.x); e1.y = __builtin_amdgcn_exp2f(g1.y);
                e0 = pk_mul(e0, Wsc);
                e1 = pk_mul(e1, Wsc);
            }
            sq0.x = __builtin_amdgcn_sqrtf(d20.x); sq0.y = __builtin_amdgcn_sqrtf(d20.y);
            sq1.x = __builtin_amdgcn_sqrtf(d21.x); sq1.y = __builtin_amdgcn_sqrtf(d21.y);
            s0 = pk_add(s0, e0);  tt0 = pk_fma(e0, sq0, tt0);
            s1 = pk_add(s1, e1);  tt1 = pk_fma(e1, sq1, tt1);
        }
    }
    atomicAdd(&stS[col0], s0.x + s0.y);
    atomicAdd(&stT[col0], tt0.x + tt0.y);
    atomicAdd(&stS[col1], s1.x + s1.y);
    atomicAdd(&stT[col1], tt1.x + tt1.y);
}

// ---------------- rowK: col-finalize prelude + row-partial stream ----------------
// MODE 1: general. MODE 2: j==8 (rs = sum remR_9, u at coefP direct).
template<int MODE, bool SPARSE>
__global__ __launch_bounds__(512) void rowK(
    const float4* __restrict__ P1, const float4* __restrict__ P2,
    const float* __restrict__ stSr, const float* __restrict__ stTr,
    float* __restrict__ stSz, float* __restrict__ stTz,
    const float* __restrict__ remRr, float* __restrict__ remRw,
    float* __restrict__ stRS, float* __restrict__ stU,
    float* __restrict__ out,
    float coefP, float coefN)
{
    __shared__ v4f tA[CH / 2];                    // {-x0,-x1,-y0,-y1}  (P2 cols)
    __shared__ v4f tB[CH / 2];                    // {-z0,-z1, Rn0, Rn1}
    __shared__ v2f tC[CH / 2];                    // {pc0, pc1}
    __shared__ float sRn[CH], sPcs[CH];
    const int chunks = MM / CH;                   // 32
    const int bpb = (NN / 1024) * chunks;         // 64
    const int batch = blockIdx.x / bpb;
    const int rem   = blockIdx.x % bpb;
    const int rg    = rem / chunks;               // 0..1
    const int ic    = rem % chunks;
    const int t     = threadIdx.x;                // 0..511

    const int row0 = batch * NN + rg * 1024 + t;
    const int row1 = row0 + 512;
    const float4 p0 = P1[row0];                   // hoisted above prelude
    const float4 p1 = P1[row1];
    float4 a, b;
    if (t < CH / 2) {                             // hoisted staging loads
        const int gl2 = batch * MM + ic * CH + 2 * t;
        a = P2[gl2];
        b = P2[gl2 + 1];
    }

    // prelude: finalize cols of this chunk (duplicated by 2 rg-blocks; identical values)
    float c = 0.0f;
    if (t < CH) {
        const int gl = batch * MM + ic * CH + t;
        const float R  = remRr[gl];
        const float s  = stSr[gl];
        const float t2 = stTr[gl];
        const float sumr = s * R;
        const float cons = fminf(R / (sumr + EPSF), 1.0f);
        const float pcol = R * cons;
        const float Rn   = fmaxf(R - sumr * cons, 0.0f);
        remRw[gl] = Rn;
        sRn[t]  = Rn;
        sPcs[t] = pcol;
        stSz[gl] = 0.0f; stTz[gl] = 0.0f;         // zero next accumulation parity
        if (rg == 0) c = pcol * t2;               // cost contribution (once per chunk)
    }
    if (rg == 0) {
#pragma unroll
        for (int off = 32; off > 0; off >>= 1) c += __shfl_xor(c, off, 64);
        if (t == 0) atomicAdd(out + batch, c);
    }
    __syncthreads();
    if (t < CH / 2) {
        tA[t] = (v4f){-a.x, -b.x, -a.y, -b.y};
        tB[t] = (v4f){-a.z, -b.z, sRn[2*t], sRn[2*t + 1]};
        tC[t] = (v2f){sPcs[2*t], sPcs[2*t + 1]};
    }
    __syncthreads();

    const v2f ax0 = {p0.x, p0.x}, ay0 = {p0.y, p0.y}, az0 = {p0.z, p0.z};
    const v2f ax1 = {p1.x, p1.x}, ay1 = {p1.y, p1.y}, az1 = {p1.z, p1.z};
    const v2f cfN = {coefN, coefN};
    const v2f cfP = {coefP, coefP};
    v2f rs0 = {0.0f, 0.0f}, rs1 = {0.0f, 0.0f};
    v2f u0  = {0.0f, 0.0f}, u1  = {0.0f, 0.0f};
#pragma unroll 4
    for (int k = 0; k < CH / 2; ++k) {
        const v4f A = tA[k], B = tB[k];
        const v2f Pc = tC[k];
        const v2f Xn = lo2(A), Yn = hi2(A), Zn = lo2(B), Rnp = hi2(B);
        const v2f dx0 = pk_add(Xn, ax0), dy0 = pk_add(Yn, ay0), dz0 = pk_add(Zn, az0);
        const v2f d20 = pk_fma(dx0, dx0, pk_fma(dy0, dy0, pk_mul(dz0, dz0)));
        const v2f dx1 = pk_add(Xn, ax1), dy1 = pk_add(Yn, ay1), dz1 = pk_add(Zn, az1);
        const v2f d21 = pk_fma(dx1, dx1, pk_fma(dy1, dy1, pk_mul(dz1, dz1)));
        if (MODE == 1) {
            const v2f g0 = pk_mul(d20, cfN), g1 = pk_mul(d21, cfN);
            bool go = true;
            if (SPARSE) {
                const float gm = fmaxf(fmaxf(g0.x, g0.y), fmaxf(g1.x, g1.y));
                go = __ballot(gm > SKIPT) != 0ull;
            }
            if (go) {
                v2f en0, en1;
                en0.x = __builtin_amdgcn_exp2f(g0.x); en0.y = __builtin_amdgcn_exp2f(g0.y);
                en1.x = __builtin_amdgcn_exp2f(g1.x); en1.y = __builtin_amdgcn_exp2f(g1.y);
                const v2f e20 = pk_mul(en0, en0), e21 = pk_mul(en1, en1);
                const v2f e40 = pk_mul(e20, e20), e41 = pk_mul(e21, e21);
                u0  = pk_fma(e40, Pc, u0);
                u1  = pk_fma(e41, Pc, u1);
                rs0 = pk_fma(en0, Rnp, rs0);
                rs1 = pk_fma(en1, Rnp, rs1);
            }
        } else {
            const v2f g0 = pk_mul(d20, cfP), g1 = pk_mul(d21, cfP);
            v2f ep0, ep1;
            ep0.x = __builtin_amdgcn_exp2f(g0.x); ep0.y = __builtin_amdgcn_exp2f(g0.y);
            ep1.x = __builtin_amdgcn_exp2f(g1.x); ep1.y = __builtin_amdgcn_exp2f(g1.y);
            u0  = pk_fma(ep0, Pc, u0);
            u1  = pk_fma(ep1, Pc, u1);
            rs0 = pk_add(rs0, Rnp);               // e_next = exp(0) = 1
            rs1 = pk_add(rs1, Rnp);
        }
    }
    atomicAdd(&stRS[row0], rs0.x + rs0.y);
    atomicAdd(&stU[row0],  u0.x + u0.y);
    atomicAdd(&stRS[row1], rs1.x + rs1.y);
    atomicAdd(&stU[row1],  u1.x + u1.y);
}

// ---------------- finCost: cost for level 9 (no state updates) ----------------
__global__ __launch_bounds__(256) void finCost(
    const float* __restrict__ stSr, const float* __restrict__ stTr,
    const float* __restrict__ remRr, float* __restrict__ out)
{
    const int idx = blockIdx.x * 256 + threadIdx.x;
    const int batch = idx / MM;
    const float R = remRr[idx];
    const float sumr = stSr[idx] * R;
    const float cons = fminf(R / (sumr + EPSF), 1.0f);
    float c = R * cons * stTr[idx];
#pragma unroll
    for (int off = 32; off > 0; off >>= 1) c += __shfl_xor(c, off, 64);
    if ((threadIdx.x & 63) == 0) atomicAdd(out + batch, c);
}

extern "C" void kernel_launch(void* const* d_in, const int* in_sizes, int n_in,
                              void* d_out, int out_size, void* d_ws, size_t ws_size,
                              hipStream_t stream)
{
    const float* xyz1 = (const float*)d_in[0];
    const float* xyz2 = (const float*)d_in[1];
    float* out = (float*)d_out;

    const int BN = BB * NN, BM = BB * MM;
    float4* P1 = (float4*)d_ws;
    float4* P2 = P1 + BN;
    float* remL  = (float*)(P2 + BM);       // [2][BN]
    float* scale = remL + 2 * BN;           // [2][BN]
    float* remR  = scale + 2 * BN;          // [2][BM]
    float* stRS  = remR + 2 * BM;           // [2][BN]
    float* stU   = stRS + 2 * BN;           // [2][BN]
    float* stS   = stU + 2 * BN;            // [2][BM]
    float* stT   = stS + 2 * BM;            // [2][BM]

    init_kernel<<<dim3(BN / 256), dim3(256), 0, stream>>>(
        xyz1, xyz2, P1, P2, remR, stRS, stU, stS, stT, out);

    // levels: j = 7..-1 -> -(4^j), then 0.  coef = level * log2(e)
    float coef[10];
    const double lv[10] = {-16384.0, -4096.0, -1024.0, -256.0, -64.0,
                           -16.0, -4.0, -1.0, -0.25, 0.0};
    for (int i = 0; i < 10; ++i) coef[i] = (float)(lv[i] * 1.4426950408889634);

    dim3 grid(BB * 2 * (MM / CH));          // 16*2*32 = 1024 blocks
    dim3 fgrid(BM / 256);                   // 128
    dim3 blk(512);
    dim3 blk256(256);

    rowInit<<<grid, blk, 0, stream>>>(P1, P2, stRS + 1 * BN, coef[0]);

    for (int j = 0; j < 10; ++j) {
        const int p = j & 1, q = 1 - p;
        if (j == 0)
            colK<0, true><<<grid, blk, 0, stream>>>(P1, P2,
                stRS + q*BN, stU + q*BN, stRS + p*BN, stU + p*BN,
                remL + p*BN, remL + q*BN, scale + p*BN, scale + q*BN,
                stS + p*BM, stT + p*BM, coef[0]);
        else if (j <= 3)
            colK<1, true><<<grid, blk, 0, stream>>>(P1, P2,
                stRS + q*BN, stU + q*BN, stRS + p*BN, stU + p*BN,
                remL + p*BN, remL + q*BN, scale + p*BN, scale + q*BN,
                stS + p*BM, stT + p*BM, coef[j]);
        else if (j == 9)
            colK<2, false><<<grid, blk, 0, stream>>>(P1, P2,
                stRS + q*BN, stU + q*BN, stRS + p*BN, stU + p*BN,
                remL + p*BN, remL + q*BN, scale + p*BN, scale + q*BN,
                stS + p*BM, stT + p*BM, coef[9]);
        else
            colK<1, false><<<grid, blk, 0, stream>>>(P1, P2,
                stRS + q*BN, stU + q*BN, stRS + p*BN, stU + p*BN,
                remL + p*BN, remL + q*BN, scale + p*BN, scale + q*BN,
                stS + p*BM, stT + p*BM, coef[j]);

        if (j < 9) {
            if (j <= 2)
                rowK<1, true><<<grid, blk, 0, stream>>>(P1, P2,
                    stS + p*BM, stT + p*BM, stS + q*BM, stT + q*BM,
                    remR + p*BM, remR + q*BM,
                    stRS + p*BN, stU + p*BN, out, coef[j], coef[j+1]);
            else if (j < 8)
                rowK<1, false><<<grid, blk, 0, stream>>>(P1, P2,
                    stS + p*BM, stT + p*BM, stS + q*BM, stT + q*BM,
                    remR + p*BM, remR + q*BM,
                    stRS + p*BN, stU + p*BN, out, coef[j], coef[j+1]);
            else
                rowK<2, false><<<grid, blk, 0, stream>>>(P1, P2,
                    stS + p*BM, stT + p*BM, stS + q*BM, stT + q*BM,
                    remR + p*BM, remR + q*BM,
                    stRS + p*BN, stU + p*BN, out, coef[8], 0.0f);
        }
    }
    // level 9 cost: stS/stT parity 1, remR parity 1
    finCost<<<fgrid, blk256, 0, stream>>>(stS + 1*BM, stT + 1*BM, remR + 1*BM, out);
}